// Round 5
// baseline (394.278 us; speedup 1.0000x reference)
//
#include <hip/hip_runtime.h>
#include <math.h>

// ---------------------------------------------------------------------------
// GAU-alpha fused block for MI355X (gfx950).
// B=64, S=512, H=512, E=1024, UV=2176, D=128, M=B*S=32768.
// bf16 MFMA (16x16x32) all matmuls; fp32 elsewhere.
// Round 12: r4 showed 2 blocks/CU still ~65% per-tile dead time (MfmaUtil 29,
// VALU 29, occ 21%). This round: 2-buffer 48 KiB staging -> 3 blocks/CU
// (24 waves/CU, m97/m114 implicit-overlap regime), depth-1 prefetch,
// vmcnt(0)-drain before the single per-tile barrier (each wave drains its own
// loads pre-barrier => all LDS valid post-barrier). Epilogue transpose tiles
// now 32 KiB half-tiles, two passes (write half / barrier / store half).
// XCD chunked remap kept (r3: FETCH 180->65 MB). Core applied to gemm1, pv,
// out; qk stays on the old 128^2 core.
// ---------------------------------------------------------------------------

#define M_TOT   32768
#define S_LEN   512
#define H_DIM   512
#define E_DIMC  1024
#define UV_DIM  2176
#define UV_PAD  2304   // padded so the 256-wide base tile reads zeros
#define D_DIM   128

using floatx4  = __attribute__((ext_vector_type(4))) float;
using uintx2   = __attribute__((ext_vector_type(2))) unsigned int;
using uintx4   = __attribute__((ext_vector_type(4))) unsigned int;
using ushortx4 = __attribute__((ext_vector_type(4))) unsigned short;
using short8   = __attribute__((ext_vector_type(8))) short;

#define ASYNC_CP16(gsrc, ldst)                                                  \
    __builtin_amdgcn_global_load_lds(                                           \
        (const __attribute__((address_space(1))) void*)(gsrc),                  \
        (__attribute__((address_space(3))) void*)(ldst), 16, 0, 0)

__device__ __forceinline__ float bf2f(unsigned short h) {
    union { unsigned int u; float f; } c;
    c.u = ((unsigned int)h) << 16;
    return c.f;
}
__device__ __forceinline__ unsigned short f2bf(float f) {
    union { float f; unsigned int u; } c;
    c.f = f;
    unsigned int r = c.u + 0x7fffu + ((c.u >> 16) & 1u);  // RNE
    return (unsigned short)(r >> 16);
}
__device__ __forceinline__ float silu_fast(float x) {
    float e = __expf(-x);                       // v_exp_f32
    return x * __builtin_amdgcn_rcpf(1.0f + e); // v_rcp_f32
}
// Chunked-bijective XCD remap: hw block b runs on XCD (b%8); give each XCD a
// CONTIGUOUS range of logical tiles so panel-sharing neighbors co-reside in
// one L2. Requires nwg % 8 == 0 (all our grids satisfy this).
__device__ __forceinline__ int xcd_remap(int b, int nwg) {
    return (b & 7) * (nwg >> 3) + (b >> 3);
}

// ---------------------------------------------------------------------------
__global__ __launch_bounds__(256) void f2bf_kernel(const float* __restrict__ in,
                                                   unsigned short* __restrict__ out,
                                                   int n4) {
    int i = blockIdx.x * 256 + threadIdx.x;
    if (i < n4) {
        floatx4 v = ((const floatx4*)in)[i];
        ushortx4 o;
        o.x = f2bf(v.x); o.y = f2bf(v.y); o.z = f2bf(v.z); o.w = f2bf(v.w);
        ((ushortx4*)out)[i] = o;
    }
}

// f2bf with zero-fill tail (pads uv_w rows 2176..2303 with zeros)
__global__ __launch_bounds__(256) void f2bf_pad_kernel(const float* __restrict__ in,
                                                       unsigned short* __restrict__ out,
                                                       int n4_src, int n4_dst) {
    int i = blockIdx.x * 256 + threadIdx.x;
    if (i < n4_dst) {
        ushortx4 o;
        if (i < n4_src) {
            floatx4 v = ((const floatx4*)in)[i];
            o.x = f2bf(v.x); o.y = f2bf(v.y); o.z = f2bf(v.z); o.w = f2bf(v.w);
        } else {
            o.x = 0; o.y = 0; o.z = 0; o.w = 0;
        }
        ((ushortx4*)out)[i] = o;
    }
}

// ---------------------------------------------------------------------------
__global__ __launch_bounds__(256) void rmsnorm_kernel(const float* __restrict__ x,
                                                      const float* __restrict__ ln_g,
                                                      unsigned short* __restrict__ xn) {
    int row  = blockIdx.x * 4 + (threadIdx.x >> 6);
    int lane = threadIdx.x & 63;
    const float* xr = x + (size_t)row * H_DIM;
    floatx4 v0 = ((const floatx4*)xr)[lane];
    floatx4 v1 = ((const floatx4*)xr)[lane + 64];
    float ss = v0.x*v0.x + v0.y*v0.y + v0.z*v0.z + v0.w*v0.w
             + v1.x*v1.x + v1.y*v1.y + v1.z*v1.z + v1.w*v1.w;
    #pragma unroll
    for (int off = 32; off > 0; off >>= 1) ss += __shfl_xor(ss, off, 64);
    float norm = sqrtf(ss) * 0.044194173824159216f;  // * H^-0.5
    float sc   = ln_g[0] / fmaxf(norm, 1e-5f);
    unsigned short* xo = xn + (size_t)row * H_DIM;
    ushortx4 o0, o1;
    o0.x = f2bf(v0.x * sc); o0.y = f2bf(v0.y * sc);
    o0.z = f2bf(v0.z * sc); o0.w = f2bf(v0.w * sc);
    o1.x = f2bf(v1.x * sc); o1.y = f2bf(v1.y * sc);
    o1.z = f2bf(v1.z * sc); o1.w = f2bf(v1.w * sc);
    ((ushortx4*)xo)[lane]      = o0;
    ((ushortx4*)xo)[lane + 64] = o1;
}

// ---------------------------------------------------------------------------
__global__ __launch_bounds__(64) void rope_table_kernel(float* __restrict__ cost,
                                                        float* __restrict__ sint) {
    int s = blockIdx.x;
    int j = threadIdx.x;  // 0..63
    float invf = (float)pow(10000.0, (double)j / 64.0);
    float ang  = (float)s * invf;  // fp32 multiply like the f32 reference
    double a   = (double)ang;
    cost[s * 64 + j] = (float)cos(a);
    sint[s * 64 + j] = (float)sin(a);
}

// ---------------------------------------------------------------------------
__global__ __launch_bounds__(256) void rope_apply_kernel(const float* __restrict__ base,
                                                         const float* __restrict__ gamma,
                                                         const float* __restrict__ beta,
                                                         const float* __restrict__ cost,
                                                         const float* __restrict__ sint,
                                                         unsigned short* __restrict__ q,
                                                         unsigned short* __restrict__ k) {
    int idx = blockIdx.x * 256 + threadIdx.x;  // M*64 total
    int m = idx >> 6;
    int j = idx & 63;
    int s = m & (S_LEN - 1);
    float b1 = base[(size_t)m * D_DIM + j];
    float b2 = base[(size_t)m * D_DIM + 64 + j];
    float c  = cost[s * 64 + j];
    float sn = sint[s * 64 + j];
    float yq1 = b1 * gamma[j]       + beta[j];
    float yq2 = b2 * gamma[64 + j]  + beta[64 + j];
    float yk1 = b1 * gamma[128 + j] + beta[128 + j];
    float yk2 = b2 * gamma[192 + j] + beta[192 + j];
    q[(size_t)m * D_DIM + j]      = f2bf(yq1 * c - yq2 * sn);
    q[(size_t)m * D_DIM + 64 + j] = f2bf(yq2 * c + yq1 * sn);
    k[(size_t)m * D_DIM + j]      = f2bf(yk1 * c - yk2 * sn);
    k[(size_t)m * D_DIM + 64 + j] = f2bf(yk2 * c + yk1 * sn);
}

// ===========================================================================
// 128x256 pipelined GEMM core, B^T form: C[m][n] = sum_k A[m][k]*B[n][k].
// 8 waves (2M x 4N), per-wave C = 64x64 (acc[4][4]). BK=32.
// 2 LDS buffers of 24 KiB = 48 KiB -> 3 blocks/CU (24 waves/CU).
// Depth-1 prefetch: stage(t+1) right after the per-tile barrier; at tile
// entry each wave drains its OWN tile-t loads (vmcnt(0)) BEFORE the barrier,
// so after the barrier every wave's staged data is in LDS. One s_barrier per
// K-tile, setprio(1) around the 16-MFMA cluster, sched_barrier(0) pins.
//
// LDS packing (per buf): logical [rows][32 k] bf16, two logical rows per
// 128B LDS row: R = row>>1; chunk c = (row&1)*4 + (k>>3); phys cp = c^(R&7).
// Staging is LDS-linear (gload_lds), inverse swizzle on the global source.
//
// Race-freedom: stage(t+1) overwrites buf[(t+1)&1]; tile t-1's reads of that
// buffer retired pre-barrier (consumed by pre-barrier MFMAs, lgkmcnt
// enforced), and stage(t+1) is issued post-barrier.
// ===========================================================================
template <bool SWAPT>
__device__ __forceinline__ void gemm128_core(const unsigned short* __restrict__ A,
                                             const unsigned short* __restrict__ B,
                                             int lda, int ldb, int K,
                                             int m0, int n0,
                                             unsigned short (&st)[2][12288],
                                             floatx4 (&acc)[4][4]) {
    const int tid  = threadIdx.x;
    const int lane = tid & 63;
    const int wave = tid >> 6;
    const int quad = lane >> 4;
    const int l16  = lane & 15;
    const int wrow = (wave >> 2) * 64;
    const int wcol = (wave & 3) * 64;

    // staging geometry: 16B chunks; A: 512 chunks (rows 0..127), B: 1024
    const int qa  = wave * 64 + lane;
    const int Ra  = qa >> 3;
    const int ca  = (qa & 7) ^ (Ra & 7);      // inverse swizzle
    const int srA = 2 * Ra + (ca >> 2);       // logical row 0..127
    const int scA = (ca & 3) * 8;             // k offset (shorts)
    const unsigned short* pa  = A + (size_t)(m0 + srA) * lda + scA;
    const unsigned short* pb0 = B + (size_t)(n0 + srA) * ldb + scA;
    const unsigned short* pb1 = pb0 + (size_t)128 * ldb;   // B rows 128..255
    const int ldsA  = (wave * 64) * 8;
    const int ldsB0 = 4096 + (wave * 64) * 8;
    const int ldsB1 = 4096 + (512 + wave * 64) * 8;

    #pragma unroll
    for (int i = 0; i < 4; i++)
        #pragma unroll
        for (int j = 0; j < 4; j++) acc[i][j] = (floatx4){0.f, 0.f, 0.f, 0.f};

    const int NT = K >> 5;
    auto stage = [&](int buf, int t) {
        unsigned short* s = &st[buf][0];
        const int kt = t * 32;
        ASYNC_CP16(pa  + kt, s + ldsA);
        ASYNC_CP16(pb0 + kt, s + ldsB0);
        ASYNC_CP16(pb1 + kt, s + ldsB1);
    };
    stage(0, 0);

    int aoff[4], boff[4];
    #pragma unroll
    for (int mt = 0; mt < 4; mt++) {
        int r  = wrow + mt * 16 + l16;        // 0..127
        int Rr = r >> 1;
        int cp = (((r & 1) << 2) + quad) ^ (Rr & 7);
        aoff[mt] = Rr * 64 + cp * 8;
    }
    #pragma unroll
    for (int nt = 0; nt < 4; nt++) {
        int r  = wcol + nt * 16 + l16;        // 0..255
        int Rr = r >> 1;
        int cp = (((r & 1) << 2) + quad) ^ (Rr & 7);
        boff[nt] = 4096 + Rr * 64 + cp * 8;
    }

    for (int t = 0; t < NT; ++t) {
        asm volatile("s_waitcnt vmcnt(0)" ::: "memory");
        __builtin_amdgcn_sched_barrier(0);   // pin: nothing crosses the wait
        __builtin_amdgcn_s_barrier();
        __builtin_amdgcn_sched_barrier(0);   // pin: ds_reads stay below barrier
        if (t + 1 < NT) stage((t + 1) & 1, t + 1);

        const unsigned short* sb = &st[t & 1][0];
        short8 af[4], bf[4];
        #pragma unroll
        for (int mt = 0; mt < 4; mt++) {
            union { short8 s8; uintx4 u4; } fu;
            fu.u4 = *(const uintx4*)&sb[aoff[mt]];
            af[mt] = fu.s8;
        }
        #pragma unroll
        for (int nt = 0; nt < 4; nt++) {
            union { short8 s8; uintx4 u4; } fu;
            fu.u4 = *(const uintx4*)&sb[boff[nt]];
            bf[nt] = fu.s8;
        }
        __builtin_amdgcn_s_setprio(1);
        #pragma unroll
        for (int mt = 0; mt < 4; mt++)
            #pragma unroll
            for (int nt = 0; nt < 4; nt++)
                acc[mt][nt] = SWAPT
                    ? __builtin_amdgcn_mfma_f32_16x16x32_bf16(bf[nt], af[mt], acc[mt][nt], 0, 0, 0)
                    : __builtin_amdgcn_mfma_f32_16x16x32_bf16(af[mt], bf[nt], acc[mt][nt], 0, 0, 0);
        __builtin_amdgcn_s_setprio(0);
    }
}

// LDS: staging (48 KiB) unioned with a 32 KiB epilogue HALF-tile.
// u/pv: T2[64 rows][256 cols]; v: T2[128 rows][128 cols]. 16B-chunk XOR
// swizzle (chunk ^ (row&15)) -> b64 writes ~2-way, b128 reads conflict-free.
// Epilogue runs in two passes (one half-tile each), barrier-uniform.
union __align__(16) Lds2 {
    unsigned short st[2][12288];   // 49152 B staging
    unsigned short T2[16384];      // 32768 B epilogue half-tile
};

// ---------------------------------------------------------------------------
// GEMM1 (merged): act = silu(xn @ uv_w^T + uv_b), grid (9, 256) xcd-remapped
//   xb <  4 : u columns, SWAPPED, swizzled half-tile transpose, b128 stores
//   xb 4..7 : v columns, UNSWAPPED, T2[n][m] transpose -> vT (b,e,s)
//   xb == 8 : base columns (uvw zero-padded to 2304), UNSWAPPED, f32 stores
// ---------------------------------------------------------------------------
__global__ __launch_bounds__(512, 2) void gemm1_128_kernel(const unsigned short* __restrict__ xn,
                                                           const unsigned short* __restrict__ uvw,
                                                           const float* __restrict__ uvb,
                                                           unsigned short* __restrict__ u,
                                                           unsigned short* __restrict__ vT,
                                                           float* __restrict__ base) {
    __shared__ Lds2 lds;
    floatx4 acc[4][4];
    const int bl = blockIdx.y * 9 + blockIdx.x;
    const int lg = xcd_remap(bl, 9 * (M_TOT / 128));  // 2304
    const int xb = lg % 9;
    const int m0 = (lg / 9) * 128;
    const int tid = threadIdx.x, lane = tid & 63, wave = tid >> 6;
    const int quad = lane >> 4, l16 = lane & 15;
    const int wrow = (wave >> 2) * 64, wcol = (wave & 3) * 64;

    if (xb < 4) {
        const int n0 = xb * 256;
        gemm128_core<true>(xn, uvw, H_DIM, H_DIM, H_DIM, m0, n0, lds.st, acc);
        __syncthreads();
        #pragma unroll
        for (int h = 0; h < 2; h++) {
            if ((wave >> 2) == h) {
                #pragma unroll
                for (int mt = 0; mt < 4; mt++) {
                    int row = mt * 16 + l16;              // local 0..63
                    #pragma unroll
                    for (int nt = 0; nt < 4; nt++) {
                        int nl = wcol + nt * 16 + quad * 4;  // 0..255
                        floatx4 b4 = *(const floatx4*)&uvb[n0 + nl];
                        ushortx4 pk;
                        #pragma unroll
                        for (int r = 0; r < 4; r++)
                            pk[r] = f2bf(silu_fast(acc[mt][nt][r] + b4[r]));
                        *(uintx2*)&lds.T2[row * 256 + (((nl >> 3) ^ (row & 15)) << 3) + (nl & 7)] = *(uintx2*)&pk;
                    }
                }
            }
            __syncthreads();
            #pragma unroll
            for (int i = 0; i < 4; i++) {
                int idx = tid + i * 512;                  // 0..2047
                int row = idx >> 5, c16 = idx & 31;
                *(uintx4*)(u + (size_t)(m0 + h * 64 + row) * E_DIMC + n0 + c16 * 8) =
                    *(const uintx4*)&lds.T2[row * 256 + ((c16 ^ (row & 15)) << 3)];
            }
            __syncthreads();
        }
    } else if (xb < 8) {
        const int n0 = xb * 256;  // 1024..1792 in act space
        gemm128_core<false>(xn, uvw, H_DIM, H_DIM, H_DIM, m0, n0, lds.st, acc);
        __syncthreads();
        const int b = m0 >> 9, sg0 = m0 & (S_LEN - 1), eg0 = n0 - E_DIMC;
        #pragma unroll
        for (int h = 0; h < 2; h++) {
            if (((wave & 3) >> 1) == h) {
                #pragma unroll
                for (int nt = 0; nt < 4; nt++) {
                    int rowL = (wave & 1) * 64 + nt * 16 + l16;   // local e 0..127
                    float bias = uvb[n0 + h * 128 + rowL];
                    #pragma unroll
                    for (int mt = 0; mt < 4; mt++) {
                        int colT = wrow + mt * 16 + quad * 4;     // m-local 0..127
                        ushortx4 pk;
                        #pragma unroll
                        for (int r = 0; r < 4; r++)
                            pk[r] = f2bf(silu_fast(acc[mt][nt][r] + bias));
                        *(uintx2*)&lds.T2[rowL * 128 + (((colT >> 3) ^ (rowL & 15)) << 3) + (colT & 7)] = *(uintx2*)&pk;
                    }
                }
            }
            __syncthreads();
            #pragma unroll
            for (int i = 0; i < 4; i++) {
                int idx = tid + i * 512;                  // 0..2047
                int e2 = idx >> 4, j = idx & 15;
                *(uintx4*)(vT + ((size_t)b * E_DIMC + eg0 + h * 128 + e2) * S_LEN + sg0 + j * 8) =
                    *(const uintx4*)&lds.T2[e2 * 128 + ((j ^ (e2 & 15)) << 3)];
            }
            __syncthreads();
        }
    } else {
        const int n0 = 2048;  // base slice; cols 128..255 hit zero-padded uvw
        gemm128_core<false>(xn, uvw, H_DIM, H_DIM, H_DIM, m0, n0, lds.st, acc);
        if ((wave & 3) < 2) {
            #pragma unroll
            for (int mt = 0; mt < 4; mt++) {
                int m = m0 + wrow + mt * 16 + quad * 4;
                #pragma unroll
                for (int nt = 0; nt < 4; nt++) {
                    int n = wcol + nt * 16 + l16;     // < 128
                    float bias = uvb[2048 + n];
                    #pragma unroll
                    for (int r = 0; r < 4; r++)
                        base[(size_t)(m + r) * D_DIM + n] = silu_fast(acc[mt][nt][r] + bias);
                }
            }
        }
    }
}

// ---------------------------------------------------------------------------
// OUT: out = oe @ o_w^T + o_b + x, 128x256 pipelined core, direct f32 stores.
// grid (2, 256) xcd-remapped; n fastest (oe A-panel L2 locality).
// ---------------------------------------------------------------------------
__global__ __launch_bounds__(512, 2) void gemm_out128_kernel(const unsigned short* __restrict__ oe,
                                                             const unsigned short* __restrict__ ow,
                                                             const float* __restrict__ ob,
                                                             const float* __restrict__ x,
                                                             float* __restrict__ out) {
    __shared__ __align__(16) unsigned short st[2][12288];
    floatx4 acc[4][4];
    const int bl = blockIdx.y * 2 + blockIdx.x;
    const int lg = xcd_remap(bl, 2 * (M_TOT / 128)); // 512
    const int n0 = (lg & 1) * 256;
    const int m0 = (lg >> 1) * 128;
    gemm128_core<true>(oe, ow, E_DIMC, E_DIMC, E_DIMC, m0, n0, st, acc);

    const int tid = threadIdx.x, lane = tid & 63, wave = tid >> 6;
    const int quad = lane >> 4, l16 = lane & 15;
    const int wrow = (wave >> 2) * 64, wcol = (wave & 3) * 64;
    #pragma unroll
    for (int mt = 0; mt < 4; mt++) {
        int m = m0 + wrow + mt * 16 + l16;
        #pragma unroll
        for (int nt = 0; nt < 4; nt++) {
            int n = n0 + wcol + nt * 16 + quad * 4;
            size_t off = (size_t)m * H_DIM + n;
            floatx4 b4 = *(const floatx4*)&ob[n];
            floatx4 x4 = *(const floatx4*)&x[off];
            *(floatx4*)&out[off] = acc[mt][nt] + b4 + x4;
        }
    }
}

// ---------------------------------------------------------------------------
// PV: u <- u .* (P @ v), 128x256 core, SWAPPED; half-tile transpose; b128 RMW.
// grid (4, 4, 64) xcd-remapped: 8 whole batches per XCD.
// ---------------------------------------------------------------------------
__global__ __launch_bounds__(512, 2) void gemm_pv128_kernel(const unsigned short* __restrict__ P,
                                                            const unsigned short* __restrict__ vT,
                                                            unsigned short* __restrict__ u) {
    __shared__ Lds2 lds;
    floatx4 acc[4][4];
    const int bl = (blockIdx.z * 4 + blockIdx.y) * 4 + blockIdx.x;
    const int lg = xcd_remap(bl, 1024);
    const int bx = lg & 3, by = (lg >> 2) & 3, bb = lg >> 4;
    const unsigned short* Pb  = P  + (size_t)bb * S_LEN * S_LEN;
    const unsigned short* vTb = vT + (size_t)bb * E_DIMC * S_LEN;
    const int m0 = bx * 128, n0 = by * 256;
    gemm128_core<true>(Pb, vTb, S_LEN, S_LEN, S_LEN, m0, n0, lds.st, acc);

    const int tid = threadIdx.x, lane = tid & 63, wave = tid >> 6;
    const int quad = lane >> 4, l16 = lane & 15;
    const int wcol = (wave & 3) * 64;
    __syncthreads();
    #pragma unroll
    for (int h = 0; h < 2; h++) {
        if ((wave >> 2) == h) {
            #pragma unroll
            for (int mt = 0; mt < 4; mt++) {
                int row = mt * 16 + l16;                  // local 0..63
                #pragma unroll
                for (int nt = 0; nt < 4; nt++) {
                    int nl = wcol + nt * 16 + quad * 4;   // 0..255
                    ushortx4 pk;
                    #pragma unroll
                    for (int r = 0; r < 4; r++) pk[r] = f2bf(acc[mt][nt][r]);
                    *(uintx2*)&lds.T2[row * 256 + (((nl >> 3) ^ (row & 15)) << 3) + (nl & 7)] = *(uintx2*)&pk;
                }
            }
        }
        __syncthreads();
        #pragma unroll
        for (int i = 0; i < 4; i++) {
            int idx = tid + i * 512;
            int row = idx >> 5, c16 = idx & 31;
            size_t off = ((size_t)bb * S_LEN + m0 + h * 64 + row) * E_DIMC + n0 + c16 * 8;
            union { uintx4 u4; unsigned short s[8]; } tv, uv, ov;
            tv.u4 = *(const uintx4*)&lds.T2[row * 256 + ((c16 ^ (row & 15)) << 3)];
            uv.u4 = *(const uintx4*)(u + off);
            #pragma unroll
            for (int jj = 0; jj < 8; jj++) ov.s[jj] = f2bf(bf2f(tv.s[jj]) * bf2f(uv.s[jj]));
            *(uintx4*)(u + off) = ov.u4;
        }
        __syncthreads();
    }
}

// ===========================================================================
// OLD 128x128 core (kept for qk)
// ===========================================================================
struct GemmLds {
    unsigned short As[128 * 64];
    unsigned short Bs[128 * 64];
};

template <bool SWAPT>
__device__ __forceinline__ void gemm_bt_core(const unsigned short* __restrict__ A,
                                             const unsigned short* __restrict__ B,
                                             int lda, int ldb, int K,
                                             int m0, int n0,
                                             GemmLds& lds, floatx4 (&acc)[4][4]) {
    const int tid  = threadIdx.x;
    const int lane = tid & 63;
    const int wave = tid >> 6;
    const int quad = lane >> 4;
    const int l16  = lane & 15;
    const int wm   = (wave >> 1) * 64;
    const int wn   = (wave & 1) * 64;
    const int lrow = lane >> 3;                    // 0..7
    const int cgs  = ((lane & 7) ^ lrow) * 8;      // swizzled source col (shorts)

    #pragma unroll
    for (int i = 0; i < 4; i++)
        #pragma unroll
        for (int j = 0; j < 4; j++) acc[i][j] = (floatx4){0.f, 0.f, 0.f, 0.f};

    for (int kt = 0; kt < K; kt += 64) {
        #pragma unroll
        for (int i = 0; i < 4; i++) {
            int r0 = wave * 32 + i * 8;
            const unsigned short* ga = A + (size_t)(m0 + r0 + lrow) * lda + kt + cgs;
            const unsigned short* gb = B + (size_t)(n0 + r0 + lrow) * ldb + kt + cgs;
            ASYNC_CP16(ga, &lds.As[r0 * 64]);
            ASYNC_CP16(gb, &lds.Bs[r0 * 64]);
        }
        __syncthreads();
        #pragma unroll
        for (int kk = 0; kk < 64; kk += 32) {
            short8 af[4], bf[4];
            const int pc = (kk + quad * 8) ^ ((l16 & 7) * 8);  // physical col
            #pragma unroll
            for (int mt = 0; mt < 4; mt++) {
                int row = wm + mt * 16 + l16;
                union { short8 s8; uintx4 u4; } fu;
                fu.u4 = *(const uintx4*)&lds.As[row * 64 + pc];
                af[mt] = fu.s8;
            }
            #pragma unroll
            for (int nt = 0; nt < 4; nt++) {
                int row = wn + nt * 16 + l16;
                union { short8 s8; uintx4 u4; } fu;
                fu.u4 = *(const uintx4*)&lds.Bs[row * 64 + pc];
                bf[nt] = fu.s8;
            }
            #pragma unroll
            for (int mt = 0; mt < 4; mt++)
                #pragma unroll
                for (int nt = 0; nt < 4; nt++)
                    acc[mt][nt] = SWAPT
                        ? __builtin_amdgcn_mfma_f32_16x16x32_bf16(bf[nt], af[mt], acc[mt][nt], 0, 0, 0)
                        : __builtin_amdgcn_mfma_f32_16x16x32_bf16(af[mt], bf[nt], acc[mt][nt], 0, 0, 0);
        }
        __syncthreads();
    }
}

union LdsU {
    GemmLds g;
    unsigned short T[128 * 128];   // 32768 B == sizeof(GemmLds)
};
__device__ __forceinline__ int swz(int row, int col) {
    return row * 128 + ((((col >> 3) ^ (row & 7)) << 3) | (col & 7));
}

// ---------------------------------------------------------------------------
// qk: P = relu((q k^T + w_bias)/sqrt(128))^2, SWAPPED, swizzled LDS transpose
// 1024 blocks (xcd-remapped: 8 whole batches per XCD)
// ---------------------------------------------------------------------------
__global__ __launch_bounds__(256) void gemm_qk_kernel(const unsigned short* __restrict__ q,
                                                      const unsigned short* __restrict__ k,
                                                      const float* __restrict__ wbias,
                                                      unsigned short* __restrict__ P) {
    __shared__ LdsU lds;
    floatx4 acc[4][4];
    const int bl = (blockIdx.z * 4 + blockIdx.y) * 4 + blockIdx.x;
    const int lg = xcd_remap(bl, 1024);
    const int bx = lg & 3, by = (lg >> 2) & 3, bz = lg >> 4;
    size_t boff = (size_t)bz * S_LEN * D_DIM;
    unsigned short* Pb = P + (size_t)bz * S_LEN * S_LEN;
    const int m0 = bx * 128, n0 = by * 128;
    gemm_bt_core<true>(q + boff, k + boff, D_DIM, D_DIM, D_DIM, m0, n0, lds.g, acc);

    const int tid = threadIdx.x, lane = tid & 63, wave = tid >> 6;
    const int quad = lane >> 4, l16 = lane & 15;
    const int wm = (wave >> 1) * 64, wn = (wave & 1) * 64;
    #pragma unroll
    for (int mt = 0; mt < 4; mt++) {
        int row = wm + mt * 16 + l16;
        int s   = m0 + row;
        #pragma unroll
        for (int nt = 0; nt < 4; nt++) {
            int nl = wn + nt * 16 + quad * 4;
            int t0 = n0 + nl;
            ushortx4 pk;
            #pragma unroll
            for (int r = 0; r < 4; r++) {
                float z = (acc[mt][nt][r] + wbias[t0 + r - s + (S_LEN - 1)]) * 0.08838834764831845f;
                z = fmaxf(z, 0.f);
                pk[r] = f2bf(z * z);
            }
            *(uintx2*)&lds.T[swz(row, nl)] = *(uintx2*)&pk;
        }
    }
    __syncthreads();
    #pragma unroll
    for (int i = 0; i < 8; i++) {
        int idx = tid + i * 256;
        int row = idx >> 4;
        int j   = idx & 15;
        *(uintx4*)(Pb + (size_t)(m0 + row) * S_LEN + n0 + j * 8) =
            *(const uintx4*)&lds.T[swz(row, j * 8)];
    }
}

// ---------------------------------------------------------------------------
extern "C" void kernel_launch(void* const* d_in, const int* in_sizes, int n_in,
                              void* d_out, int out_size, void* d_ws, size_t ws_size,
                              hipStream_t stream) {
    const float* x     = (const float*)d_in[0];
    const float* ln_g  = (const float*)d_in[1];
    const float* uv_w  = (const float*)d_in[2];
    const float* uv_b  = (const float*)d_in[3];
    const float* gamma = (const float*)d_in[4];
    const float* beta  = (const float*)d_in[5];
    const float* wbias = (const float*)d_in[6];
    const float* o_w   = (const float*)d_in[7];
    const float* o_b   = (const float*)d_in[8];
    float* out = (float*)d_out;

    char* ws = (char*)d_ws;
    size_t off = 0;
    auto alloc = [&](size_t bytes) {
        void* p = ws + off;
        off += (bytes + 255) & ~(size_t)255;
        return p;
    };
    // Peak ~196.5 MiB:
    unsigned short* u     = (unsigned short*)alloc((size_t)M_TOT * E_DIMC * 2);      // 64 MiB (u, then oe in place)
    unsigned short* vT    = (unsigned short*)alloc((size_t)64 * E_DIMC * S_LEN * 2); // 64 MiB
    unsigned short* xn    = (unsigned short*)alloc((size_t)M_TOT * H_DIM * 2);       // 32 MiB
    unsigned short* P     = xn;                                                      // alias (xn dead after gemm1)
    float*          base  = (float*)alloc((size_t)M_TOT * D_DIM * 4);                // 16 MiB
    unsigned short* q     = (unsigned short*)alloc((size_t)M_TOT * D_DIM * 2);       // 8 MiB
    unsigned short* k     = (unsigned short*)alloc((size_t)M_TOT * D_DIM * 2);       // 8 MiB
    float*          cost  = (float*)alloc((size_t)S_LEN * 64 * 4);
    float*          sint  = (float*)alloc((size_t)S_LEN * 64 * 4);
    unsigned short* uvwb  = (unsigned short*)alloc((size_t)UV_PAD * H_DIM * 2);      // 2.25 MiB (zero-padded)
    unsigned short* owb   = (unsigned short*)alloc((size_t)H_DIM * E_DIMC * 2);      // 1 MiB
    (void)ws_size; (void)in_sizes; (void)n_in; (void)out_size;

    f2bf_pad_kernel<<<(UV_PAD * H_DIM / 4 + 255) / 256, 256, 0, stream>>>(
        uv_w, uvwb, UV_DIM * H_DIM / 4, UV_PAD * H_DIM / 4);
    f2bf_kernel<<<(H_DIM * E_DIMC / 4 + 255) / 256, 256, 0, stream>>>(o_w, owb, H_DIM * E_DIMC / 4);
    rope_table_kernel<<<S_LEN, 64, 0, stream>>>(cost, sint);

    rmsnorm_kernel<<<M_TOT / 4, 256, 0, stream>>>(x, ln_g, xn);

    // gemm1 + silu (merged, 128x256 pipelined, 3 blocks/CU): u / vT / base
    gemm1_128_kernel<<<dim3(9, M_TOT / 128), 512, 0, stream>>>(xn, uvwb, uv_b, u, vT, base);

    rope_apply_kernel<<<M_TOT * 64 / 256, 256, 0, stream>>>(base, gamma, beta, cost, sint, q, k);

    // P = relu^2((q k^T + bias)/sqrt(128))   (overwrites xn region)
    gemm_qk_kernel<<<dim3(S_LEN / 128, S_LEN / 128, 64), 256, 0, stream>>>(q, k, wbias, P);

    // u <- u .* (P @ v)  in place (128x256 pipelined)
    gemm_pv128_kernel<<<dim3(S_LEN / 128, E_DIMC / 256, 64), 512, 0, stream>>>(P, vT, u);

    // out = oe @ o_w^T + o_b + x (128x256 pipelined)
    gemm_out128_kernel<<<dim3(H_DIM / 256, M_TOT / 128), 512, 0, stream>>>(u, owb, o_b, x, out);
}

// Round 6
// 357.647 us; speedup vs baseline: 1.1024x; 1.1024x over previous
//
#include <hip/hip_runtime.h>
#include <math.h>

// ---------------------------------------------------------------------------
// GAU-alpha fused block for MI355X (gfx950).
// B=64, S=512, H=512, E=1024, UV=2176, D=128, M=B*S=32768.
// bf16 MFMA (16x16x32) all matmuls; fp32 elsewhere.
// Round 13: recombination of per-kernel bests (r5 lesson: occupancy does not
// rise with smaller LDS at this shape; depth-2 counted vmcnt > depth-1 drain).
//  - gemm1: r4 core: 128x256, BK=32, 3 bufs (72 KiB), depth-2, vmcnt(3) [112us]
//  - out  : r3 core: 256x256, BK=32, 4 bufs (128 KiB), depth-3, vmcnt(8), 1/CU
//  - pv,qk: old 128^2 drain core (r3 config)
// XCD chunked-bijective remap on all GEMM grids (r3: FETCH 180->65 MB).
// ---------------------------------------------------------------------------

#define M_TOT   32768
#define S_LEN   512
#define H_DIM   512
#define E_DIMC  1024
#define UV_DIM  2176
#define UV_PAD  2304   // padded so the 256-wide base tile reads zeros
#define D_DIM   128

using floatx4  = __attribute__((ext_vector_type(4))) float;
using uintx2   = __attribute__((ext_vector_type(2))) unsigned int;
using uintx4   = __attribute__((ext_vector_type(4))) unsigned int;
using ushortx4 = __attribute__((ext_vector_type(4))) unsigned short;
using short8   = __attribute__((ext_vector_type(8))) short;

#define ASYNC_CP16(gsrc, ldst)                                                  \
    __builtin_amdgcn_global_load_lds(                                           \
        (const __attribute__((address_space(1))) void*)(gsrc),                  \
        (__attribute__((address_space(3))) void*)(ldst), 16, 0, 0)

__device__ __forceinline__ float bf2f(unsigned short h) {
    union { unsigned int u; float f; } c;
    c.u = ((unsigned int)h) << 16;
    return c.f;
}
__device__ __forceinline__ unsigned short f2bf(float f) {
    union { float f; unsigned int u; } c;
    c.f = f;
    unsigned int r = c.u + 0x7fffu + ((c.u >> 16) & 1u);  // RNE
    return (unsigned short)(r >> 16);
}
__device__ __forceinline__ float silu_fast(float x) {
    float e = __expf(-x);                       // v_exp_f32
    return x * __builtin_amdgcn_rcpf(1.0f + e); // v_rcp_f32
}
// Chunked-bijective XCD remap: hw block b runs on XCD (b%8); give each XCD a
// CONTIGUOUS range of logical tiles so panel-sharing neighbors co-reside in
// one L2. Requires nwg % 8 == 0 (all our grids satisfy this).
__device__ __forceinline__ int xcd_remap(int b, int nwg) {
    return (b & 7) * (nwg >> 3) + (b >> 3);
}

// ---------------------------------------------------------------------------
__global__ __launch_bounds__(256) void f2bf_kernel(const float* __restrict__ in,
                                                   unsigned short* __restrict__ out,
                                                   int n4) {
    int i = blockIdx.x * 256 + threadIdx.x;
    if (i < n4) {
        floatx4 v = ((const floatx4*)in)[i];
        ushortx4 o;
        o.x = f2bf(v.x); o.y = f2bf(v.y); o.z = f2bf(v.z); o.w = f2bf(v.w);
        ((ushortx4*)out)[i] = o;
    }
}

// f2bf with zero-fill tail (pads uv_w rows 2176..2303 with zeros)
__global__ __launch_bounds__(256) void f2bf_pad_kernel(const float* __restrict__ in,
                                                       unsigned short* __restrict__ out,
                                                       int n4_src, int n4_dst) {
    int i = blockIdx.x * 256 + threadIdx.x;
    if (i < n4_dst) {
        ushortx4 o;
        if (i < n4_src) {
            floatx4 v = ((const floatx4*)in)[i];
            o.x = f2bf(v.x); o.y = f2bf(v.y); o.z = f2bf(v.z); o.w = f2bf(v.w);
        } else {
            o.x = 0; o.y = 0; o.z = 0; o.w = 0;
        }
        ((ushortx4*)out)[i] = o;
    }
}

// ---------------------------------------------------------------------------
__global__ __launch_bounds__(256) void rmsnorm_kernel(const float* __restrict__ x,
                                                      const float* __restrict__ ln_g,
                                                      unsigned short* __restrict__ xn) {
    int row  = blockIdx.x * 4 + (threadIdx.x >> 6);
    int lane = threadIdx.x & 63;
    const float* xr = x + (size_t)row * H_DIM;
    floatx4 v0 = ((const floatx4*)xr)[lane];
    floatx4 v1 = ((const floatx4*)xr)[lane + 64];
    float ss = v0.x*v0.x + v0.y*v0.y + v0.z*v0.z + v0.w*v0.w
             + v1.x*v1.x + v1.y*v1.y + v1.z*v1.z + v1.w*v1.w;
    #pragma unroll
    for (int off = 32; off > 0; off >>= 1) ss += __shfl_xor(ss, off, 64);
    float norm = sqrtf(ss) * 0.044194173824159216f;  // * H^-0.5
    float sc   = ln_g[0] / fmaxf(norm, 1e-5f);
    unsigned short* xo = xn + (size_t)row * H_DIM;
    ushortx4 o0, o1;
    o0.x = f2bf(v0.x * sc); o0.y = f2bf(v0.y * sc);
    o0.z = f2bf(v0.z * sc); o0.w = f2bf(v0.w * sc);
    o1.x = f2bf(v1.x * sc); o1.y = f2bf(v1.y * sc);
    o1.z = f2bf(v1.z * sc); o1.w = f2bf(v1.w * sc);
    ((ushortx4*)xo)[lane]      = o0;
    ((ushortx4*)xo)[lane + 64] = o1;
}

// ---------------------------------------------------------------------------
__global__ __launch_bounds__(64) void rope_table_kernel(float* __restrict__ cost,
                                                        float* __restrict__ sint) {
    int s = blockIdx.x;
    int j = threadIdx.x;  // 0..63
    float invf = (float)pow(10000.0, (double)j / 64.0);
    float ang  = (float)s * invf;  // fp32 multiply like the f32 reference
    double a   = (double)ang;
    cost[s * 64 + j] = (float)cos(a);
    sint[s * 64 + j] = (float)sin(a);
}

// ---------------------------------------------------------------------------
__global__ __launch_bounds__(256) void rope_apply_kernel(const float* __restrict__ base,
                                                         const float* __restrict__ gamma,
                                                         const float* __restrict__ beta,
                                                         const float* __restrict__ cost,
                                                         const float* __restrict__ sint,
                                                         unsigned short* __restrict__ q,
                                                         unsigned short* __restrict__ k) {
    int idx = blockIdx.x * 256 + threadIdx.x;  // M*64 total
    int m = idx >> 6;
    int j = idx & 63;
    int s = m & (S_LEN - 1);
    float b1 = base[(size_t)m * D_DIM + j];
    float b2 = base[(size_t)m * D_DIM + 64 + j];
    float c  = cost[s * 64 + j];
    float sn = sint[s * 64 + j];
    float yq1 = b1 * gamma[j]       + beta[j];
    float yq2 = b2 * gamma[64 + j]  + beta[64 + j];
    float yk1 = b1 * gamma[128 + j] + beta[128 + j];
    float yk2 = b2 * gamma[192 + j] + beta[192 + j];
    q[(size_t)m * D_DIM + j]      = f2bf(yq1 * c - yq2 * sn);
    q[(size_t)m * D_DIM + 64 + j] = f2bf(yq2 * c + yq1 * sn);
    k[(size_t)m * D_DIM + j]      = f2bf(yk1 * c - yk2 * sn);
    k[(size_t)m * D_DIM + 64 + j] = f2bf(yk2 * c + yk1 * sn);
}

// ===========================================================================
// 128x256 pipelined GEMM core (r4-proven, best gemm1): 8 waves (2M x 4N),
// per-wave C = 64x64 (acc[4][4]). BK=32. 3 LDS bufs of 24 KiB = 72 KiB.
// Depth-2 prefetch, counted vmcnt(3) (0 only at final tile), 1 s_barrier per
// K-tile, setprio(1) around MFMA cluster, sched_barrier(0) pins.
// LDS packing (per buf): two logical rows per 128B LDS row, XOR swizzle:
//   R = row>>1; c = (row&1)*4 + (k>>3); phys cp = c^(R&7).
// Staging LDS-linear (gload_lds), inverse swizzle on global source.
// Race-freedom: stage(t+2) overwrites buf[(t-1)%3], whose reads retired
// before the tile-t barrier; vmcnt(3) at entry = tile-t loads landed.
// ===========================================================================
template <bool SWAPT>
__device__ __forceinline__ void gemm128_core(const unsigned short* __restrict__ A,
                                             const unsigned short* __restrict__ B,
                                             int lda, int ldb, int K,
                                             int m0, int n0,
                                             unsigned short (&st)[3][12288],
                                             floatx4 (&acc)[4][4]) {
    const int tid  = threadIdx.x;
    const int lane = tid & 63;
    const int wave = tid >> 6;
    const int quad = lane >> 4;
    const int l16  = lane & 15;
    const int wrow = (wave >> 2) * 64;
    const int wcol = (wave & 3) * 64;

    const int qa  = wave * 64 + lane;
    const int Ra  = qa >> 3;
    const int ca  = (qa & 7) ^ (Ra & 7);      // inverse swizzle
    const int srA = 2 * Ra + (ca >> 2);       // logical row 0..127
    const int scA = (ca & 3) * 8;             // k offset (shorts)
    const unsigned short* pa  = A + (size_t)(m0 + srA) * lda + scA;
    const unsigned short* pb0 = B + (size_t)(n0 + srA) * ldb + scA;
    const unsigned short* pb1 = pb0 + (size_t)128 * ldb;   // B rows 128..255
    const int ldsA  = (wave * 64) * 8;
    const int ldsB0 = 4096 + (wave * 64) * 8;
    const int ldsB1 = 4096 + (512 + wave * 64) * 8;

    #pragma unroll
    for (int i = 0; i < 4; i++)
        #pragma unroll
        for (int j = 0; j < 4; j++) acc[i][j] = (floatx4){0.f, 0.f, 0.f, 0.f};

    const int NT = K >> 5;
    auto stage = [&](int buf, int t) {
        unsigned short* s = &st[buf][0];
        const int kt = t * 32;
        ASYNC_CP16(pa  + kt, s + ldsA);
        ASYNC_CP16(pb0 + kt, s + ldsB0);
        ASYNC_CP16(pb1 + kt, s + ldsB1);
    };
    stage(0, 0);
    stage(1, 1);

    int aoff[4], boff[4];
    #pragma unroll
    for (int mt = 0; mt < 4; mt++) {
        int r  = wrow + mt * 16 + l16;        // 0..127
        int Rr = r >> 1;
        int cp = (((r & 1) << 2) + quad) ^ (Rr & 7);
        aoff[mt] = Rr * 64 + cp * 8;
    }
    #pragma unroll
    for (int nt = 0; nt < 4; nt++) {
        int r  = wcol + nt * 16 + l16;        // 0..255
        int Rr = r >> 1;
        int cp = (((r & 1) << 2) + quad) ^ (Rr & 7);
        boff[nt] = 4096 + Rr * 64 + cp * 8;
    }

    int bc = 0, bs = 2;
    for (int t = 0; t < NT; ++t) {
        if (t < NT - 1) asm volatile("s_waitcnt vmcnt(3)" ::: "memory");
        else            asm volatile("s_waitcnt vmcnt(0)" ::: "memory");
        __builtin_amdgcn_sched_barrier(0);   // pin: nothing crosses the wait
        __builtin_amdgcn_s_barrier();
        __builtin_amdgcn_sched_barrier(0);   // pin: ds_reads stay below barrier
        if (t + 2 < NT) stage(bs, t + 2);

        const unsigned short* sb = &st[bc][0];
        short8 af[4], bf[4];
        #pragma unroll
        for (int mt = 0; mt < 4; mt++) {
            union { short8 s8; uintx4 u4; } fu;
            fu.u4 = *(const uintx4*)&sb[aoff[mt]];
            af[mt] = fu.s8;
        }
        #pragma unroll
        for (int nt = 0; nt < 4; nt++) {
            union { short8 s8; uintx4 u4; } fu;
            fu.u4 = *(const uintx4*)&sb[boff[nt]];
            bf[nt] = fu.s8;
        }
        __builtin_amdgcn_s_setprio(1);
        #pragma unroll
        for (int mt = 0; mt < 4; mt++)
            #pragma unroll
            for (int nt = 0; nt < 4; nt++)
                acc[mt][nt] = SWAPT
                    ? __builtin_amdgcn_mfma_f32_16x16x32_bf16(bf[nt], af[mt], acc[mt][nt], 0, 0, 0)
                    : __builtin_amdgcn_mfma_f32_16x16x32_bf16(af[mt], bf[nt], acc[mt][nt], 0, 0, 0);
        __builtin_amdgcn_s_setprio(0);

        bc = (bc == 2) ? 0 : bc + 1;
        bs = (bs == 2) ? 0 : bs + 1;
    }
}

// LDS: staging (72 KiB) unioned with the epilogue transpose tile (64 KiB).
// u: T[128 rows][256 cols]; v: T[256 rows][128 cols]. 16B-chunk XOR
// swizzle (chunk ^ (row&15)) -> b64 writes ~2-way, b128 reads conflict-free.
union __align__(16) Lds3 {
    unsigned short st[3][12288];   // 73728 B staging
    unsigned short T[128 * 256];   // 65536 B epilogue
};

// ---------------------------------------------------------------------------
// GEMM1 (merged): act = silu(xn @ uv_w^T + uv_b), grid (9, 256) xcd-remapped
//   xb <  4 : u columns, SWAPPED, swizzled LDS transpose, b128 stores
//   xb 4..7 : v columns, UNSWAPPED, T[n][m] transpose -> vT (b,e,s)
//   xb == 8 : base columns (uvw zero-padded to 2304), UNSWAPPED, f32 stores
// ---------------------------------------------------------------------------
__global__ __launch_bounds__(512, 2) void gemm1_128_kernel(const unsigned short* __restrict__ xn,
                                                           const unsigned short* __restrict__ uvw,
                                                           const float* __restrict__ uvb,
                                                           unsigned short* __restrict__ u,
                                                           unsigned short* __restrict__ vT,
                                                           float* __restrict__ base) {
    __shared__ Lds3 lds;
    floatx4 acc[4][4];
    const int bl = blockIdx.y * 9 + blockIdx.x;
    const int lg = xcd_remap(bl, 9 * (M_TOT / 128));  // 2304
    const int xb = lg % 9;
    const int m0 = (lg / 9) * 128;
    const int tid = threadIdx.x, lane = tid & 63, wave = tid >> 6;
    const int quad = lane >> 4, l16 = lane & 15;
    const int wrow = (wave >> 2) * 64, wcol = (wave & 3) * 64;

    if (xb < 4) {
        const int n0 = xb * 256;
        gemm128_core<true>(xn, uvw, H_DIM, H_DIM, H_DIM, m0, n0, lds.st, acc);
        __syncthreads();
        #pragma unroll
        for (int mt = 0; mt < 4; mt++) {
            int row = wrow + mt * 16 + l16;           // 0..127
            #pragma unroll
            for (int nt = 0; nt < 4; nt++) {
                int nl = wcol + nt * 16 + quad * 4;   // 0..255
                floatx4 b4 = *(const floatx4*)&uvb[n0 + nl];
                ushortx4 pk;
                #pragma unroll
                for (int r = 0; r < 4; r++)
                    pk[r] = f2bf(silu_fast(acc[mt][nt][r] + b4[r]));
                *(uintx2*)&lds.T[row * 256 + (((nl >> 3) ^ (row & 15)) << 3) + (nl & 7)] = *(uintx2*)&pk;
            }
        }
        __syncthreads();
        #pragma unroll
        for (int i = 0; i < 8; i++) {
            int idx = tid + i * 512;                  // 0..4095
            int row = idx >> 5, c16 = idx & 31;
            *(uintx4*)(u + (size_t)(m0 + row) * E_DIMC + n0 + c16 * 8) =
                *(const uintx4*)&lds.T[row * 256 + ((c16 ^ (row & 15)) << 3)];
        }
    } else if (xb < 8) {
        const int n0 = xb * 256;  // 1024..1792 in act space
        gemm128_core<false>(xn, uvw, H_DIM, H_DIM, H_DIM, m0, n0, lds.st, acc);
        __syncthreads();
        #pragma unroll
        for (int nt = 0; nt < 4; nt++) {
            int rowT = wcol + nt * 16 + l16;          // n-local 0..255
            float bias = uvb[n0 + rowT];
            #pragma unroll
            for (int mt = 0; mt < 4; mt++) {
                int colT = wrow + mt * 16 + quad * 4; // m-local 0..127
                ushortx4 pk;
                #pragma unroll
                for (int r = 0; r < 4; r++)
                    pk[r] = f2bf(silu_fast(acc[mt][nt][r] + bias));
                *(uintx2*)&lds.T[rowT * 128 + (((colT >> 3) ^ (rowT & 15)) << 3) + (colT & 7)] = *(uintx2*)&pk;
            }
        }
        __syncthreads();
        const int b = m0 >> 9, sg0 = m0 & (S_LEN - 1), eg0 = n0 - E_DIMC;
        #pragma unroll
        for (int i = 0; i < 8; i++) {
            int idx = tid + i * 512;                  // 0..4095
            int e = idx >> 4, j = idx & 15;
            *(uintx4*)(vT + ((size_t)b * E_DIMC + eg0 + e) * S_LEN + sg0 + j * 8) =
                *(const uintx4*)&lds.T[e * 128 + ((j ^ (e & 15)) << 3)];
        }
    } else {
        const int n0 = 2048;  // base slice; cols 128..255 hit zero-padded uvw
        gemm128_core<false>(xn, uvw, H_DIM, H_DIM, H_DIM, m0, n0, lds.st, acc);
        if ((wave & 3) < 2) {
            #pragma unroll
            for (int mt = 0; mt < 4; mt++) {
                int m = m0 + wrow + mt * 16 + quad * 4;
                #pragma unroll
                for (int nt = 0; nt < 4; nt++) {
                    int n = wcol + nt * 16 + l16;     // < 128
                    float bias = uvb[2048 + n];
                    #pragma unroll
                    for (int r = 0; r < 4; r++)
                        base[(size_t)(m + r) * D_DIM + n] = silu_fast(acc[mt][nt][r] + bias);
                }
            }
        }
    }
}

// ===========================================================================
// 256x256 pipelined GEMM core (r3-proven, best gemm_out): 8 waves (2M x 4N),
// per-wave C = 128x64 (acc[8][4]). BK=32. 4 LDS bufs (128 KiB), depth-3
// prefetch, counted vmcnt(8)/(4)/(0) tail, 1 s_barrier per K-tile,
// setprio(1) around MFMA clusters, sched_barrier(0) pins.
// ===========================================================================
template <bool SWAPT>
__device__ __forceinline__ void gemm256_core(const unsigned short* __restrict__ A,
                                             const unsigned short* __restrict__ B,
                                             int lda, int ldb, int K,
                                             int m0, int n0,
                                             unsigned short (&st)[4][2][128][64],
                                             floatx4 (&acc)[8][4]) {
    const int tid  = threadIdx.x;
    const int lane = tid & 63;
    const int wave = tid >> 6;
    const int quad = lane >> 4;
    const int l16  = lane & 15;
    const int wrow = (wave >> 2) * 128;
    const int wcol = (wave & 3) * 64;

    const int q0    = wave * 128 + lane;        // linear 16B chunk, i=0
    const int R0    = q0 >> 3;                  // LDS row (i=1: +8)
    const int cp0   = q0 & 7;                   // physical chunk in row
    const int c0    = cp0 ^ (R0 & 7);           // logical chunk (inverse swz)
    const int srow0 = 2 * R0 + (c0 >> 2);       // logical tile row (i=1: +16)
    const int scol0 = (c0 & 3) * 8;             // k-offset in shorts

    const unsigned short* pa0 = A + (size_t)(m0 + srow0) * lda + scol0;
    const unsigned short* pa1 = pa0 + (size_t)16 * lda;
    const unsigned short* pb0 = B + (size_t)(n0 + srow0) * ldb + scol0;
    const unsigned short* pb1 = pb0 + (size_t)16 * ldb;
    const int ldsOff0 = (wave * 128) * 8;       // ushort index of uniform base
    const int ldsOff1 = (wave * 128 + 64) * 8;

    #pragma unroll
    for (int i = 0; i < 8; i++)
        #pragma unroll
        for (int j = 0; j < 4; j++) acc[i][j] = (floatx4){0.f, 0.f, 0.f, 0.f};

    const int NT = K >> 5;
    auto stage = [&](int t) {
        unsigned short* sA = &st[t & 3][0][0][0];
        unsigned short* sB = &st[t & 3][1][0][0];
        const int kt = t * 32;
        ASYNC_CP16(pa0 + kt, sA + ldsOff0);
        ASYNC_CP16(pa1 + kt, sA + ldsOff1);
        ASYNC_CP16(pb0 + kt, sB + ldsOff0);
        ASYNC_CP16(pb1 + kt, sB + ldsOff1);
    };
    stage(0);
    stage(1);
    stage(2);

    int aoff[8], boff[4];
    #pragma unroll
    for (int mt = 0; mt < 8; mt++) {
        int r  = wrow + mt * 16 + l16;
        int Rr = r >> 1;
        int cp = (((r & 1) << 2) + quad) ^ (Rr & 7);
        aoff[mt] = Rr * 64 + cp * 8;
    }
    #pragma unroll
    for (int nt = 0; nt < 4; nt++) {
        int r  = wcol + nt * 16 + l16;
        int Rr = r >> 1;
        int cp = (((r & 1) << 2) + quad) ^ (Rr & 7);
        boff[nt] = Rr * 64 + cp * 8;
    }

    for (int t = 0; t < NT; ++t) {
        if (t < NT - 2)       asm volatile("s_waitcnt vmcnt(8)" ::: "memory");
        else if (t == NT - 2) asm volatile("s_waitcnt vmcnt(4)" ::: "memory");
        else                  asm volatile("s_waitcnt vmcnt(0)" ::: "memory");
        __builtin_amdgcn_sched_barrier(0);
        __builtin_amdgcn_s_barrier();
        __builtin_amdgcn_sched_barrier(0);
        if (t + 3 < NT) stage(t + 3);

        const unsigned short* sA = &st[t & 3][0][0][0];
        const unsigned short* sB = &st[t & 3][1][0][0];
        short8 bf[4];
        #pragma unroll
        for (int nt = 0; nt < 4; nt++) {
            union { short8 s8; uintx4 u4; } fu;
            fu.u4 = *(const uintx4*)&sB[boff[nt]];
            bf[nt] = fu.s8;
        }
        #pragma unroll
        for (int half = 0; half < 2; half++) {
            short8 af[4];
            #pragma unroll
            for (int mt = 0; mt < 4; mt++) {
                union { short8 s8; uintx4 u4; } fu;
                fu.u4 = *(const uintx4*)&sA[aoff[half * 4 + mt]];
                af[mt] = fu.s8;
            }
            __builtin_amdgcn_s_setprio(1);
            #pragma unroll
            for (int mt = 0; mt < 4; mt++)
                #pragma unroll
                for (int nt = 0; nt < 4; nt++)
                    acc[half * 4 + mt][nt] = SWAPT
                        ? __builtin_amdgcn_mfma_f32_16x16x32_bf16(bf[nt], af[mt], acc[half * 4 + mt][nt], 0, 0, 0)
                        : __builtin_amdgcn_mfma_f32_16x16x32_bf16(af[mt], bf[nt], acc[half * 4 + mt][nt], 0, 0, 0);
            __builtin_amdgcn_s_setprio(0);
        }
    }
}

// ---------------------------------------------------------------------------
// OUT: out = oe @ o_w^T + o_b + x, 256^2 pipelined core, direct f32 stores.
// 256 blocks (xcd-remapped: each XCD owns 16 m-panels; ow 1 MB L2-resident).
// ---------------------------------------------------------------------------
__global__ __launch_bounds__(512, 2) void gemm_out256_kernel(const unsigned short* __restrict__ oe,
                                                             const unsigned short* __restrict__ ow,
                                                             const float* __restrict__ ob,
                                                             const float* __restrict__ x,
                                                             float* __restrict__ out) {
    __shared__ __align__(16) unsigned short st[4][2][128][64];
    floatx4 acc[8][4];
    const int bl = blockIdx.y * 2 + blockIdx.x;
    const int lg = xcd_remap(bl, 2 * (M_TOT / 256)); // 256
    const int n0 = (lg & 1) * 256;
    const int m0 = (lg >> 1) * 256;
    gemm256_core<true>(oe, ow, E_DIMC, E_DIMC, E_DIMC, m0, n0, st, acc);

    const int tid = threadIdx.x, lane = tid & 63, wave = tid >> 6;
    const int quad = lane >> 4, l16 = lane & 15;
    const int wrow = (wave >> 2) * 128, wcol = (wave & 3) * 64;
    #pragma unroll
    for (int mt = 0; mt < 8; mt++) {
        int m = m0 + wrow + mt * 16 + l16;
        #pragma unroll
        for (int nt = 0; nt < 4; nt++) {
            int n = n0 + wcol + nt * 16 + quad * 4;
            size_t off = (size_t)m * H_DIM + n;
            floatx4 b4 = *(const floatx4*)&ob[n];
            floatx4 x4 = *(const floatx4*)&x[off];
            *(floatx4*)&out[off] = acc[mt][nt] + b4 + x4;
        }
    }
}

// ===========================================================================
// OLD 128x128 drain core (kept for qk / pv — r3-measured best for both)
// ===========================================================================
struct GemmLds {
    unsigned short As[128 * 64];
    unsigned short Bs[128 * 64];
};

template <bool SWAPT>
__device__ __forceinline__ void gemm_bt_core(const unsigned short* __restrict__ A,
                                             const unsigned short* __restrict__ B,
                                             int lda, int ldb, int K,
                                             int m0, int n0,
                                             GemmLds& lds, floatx4 (&acc)[4][4]) {
    const int tid  = threadIdx.x;
    const int lane = tid & 63;
    const int wave = tid >> 6;
    const int quad = lane >> 4;
    const int l16  = lane & 15;
    const int wm   = (wave >> 1) * 64;
    const int wn   = (wave & 1) * 64;
    const int lrow = lane >> 3;                    // 0..7
    const int cgs  = ((lane & 7) ^ lrow) * 8;      // swizzled source col (shorts)

    #pragma unroll
    for (int i = 0; i < 4; i++)
        #pragma unroll
        for (int j = 0; j < 4; j++) acc[i][j] = (floatx4){0.f, 0.f, 0.f, 0.f};

    for (int kt = 0; kt < K; kt += 64) {
        #pragma unroll
        for (int i = 0; i < 4; i++) {
            int r0 = wave * 32 + i * 8;
            const unsigned short* ga = A + (size_t)(m0 + r0 + lrow) * lda + kt + cgs;
            const unsigned short* gb = B + (size_t)(n0 + r0 + lrow) * ldb + kt + cgs;
            ASYNC_CP16(ga, &lds.As[r0 * 64]);
            ASYNC_CP16(gb, &lds.Bs[r0 * 64]);
        }
        __syncthreads();
        #pragma unroll
        for (int kk = 0; kk < 64; kk += 32) {
            short8 af[4], bf[4];
            const int pc = (kk + quad * 8) ^ ((l16 & 7) * 8);  // physical col
            #pragma unroll
            for (int mt = 0; mt < 4; mt++) {
                int row = wm + mt * 16 + l16;
                union { short8 s8; uintx4 u4; } fu;
                fu.u4 = *(const uintx4*)&lds.As[row * 64 + pc];
                af[mt] = fu.s8;
            }
            #pragma unroll
            for (int nt = 0; nt < 4; nt++) {
                int row = wn + nt * 16 + l16;
                union { short8 s8; uintx4 u4; } fu;
                fu.u4 = *(const uintx4*)&lds.Bs[row * 64 + pc];
                bf[nt] = fu.s8;
            }
            #pragma unroll
            for (int mt = 0; mt < 4; mt++)
                #pragma unroll
                for (int nt = 0; nt < 4; nt++)
                    acc[mt][nt] = SWAPT
                        ? __builtin_amdgcn_mfma_f32_16x16x32_bf16(bf[nt], af[mt], acc[mt][nt], 0, 0, 0)
                        : __builtin_amdgcn_mfma_f32_16x16x32_bf16(af[mt], bf[nt], acc[mt][nt], 0, 0, 0);
        }
        __syncthreads();
    }
}

union LdsU {
    GemmLds g;
    unsigned short T[128 * 128];   // 32768 B == sizeof(GemmLds)
};
__device__ __forceinline__ int swz(int row, int col) {
    return row * 128 + ((((col >> 3) ^ (row & 7)) << 3) | (col & 7));
}

// ---------------------------------------------------------------------------
// qk: P = relu((q k^T + w_bias)/sqrt(128))^2, SWAPPED, swizzled LDS transpose
// 1024 blocks (xcd-remapped: 8 whole batches per XCD)
// ---------------------------------------------------------------------------
__global__ __launch_bounds__(256) void gemm_qk_kernel(const unsigned short* __restrict__ q,
                                                      const unsigned short* __restrict__ k,
                                                      const float* __restrict__ wbias,
                                                      unsigned short* __restrict__ P) {
    __shared__ LdsU lds;
    floatx4 acc[4][4];
    const int bl = (blockIdx.z * 4 + blockIdx.y) * 4 + blockIdx.x;
    const int lg = xcd_remap(bl, 1024);
    const int bx = lg & 3, by = (lg >> 2) & 3, bz = lg >> 4;
    size_t boff = (size_t)bz * S_LEN * D_DIM;
    unsigned short* Pb = P + (size_t)bz * S_LEN * S_LEN;
    const int m0 = bx * 128, n0 = by * 128;
    gemm_bt_core<true>(q + boff, k + boff, D_DIM, D_DIM, D_DIM, m0, n0, lds.g, acc);

    const int tid = threadIdx.x, lane = tid & 63, wave = tid >> 6;
    const int quad = lane >> 4, l16 = lane & 15;
    const int wm = (wave >> 1) * 64, wn = (wave & 1) * 64;
    #pragma unroll
    for (int mt = 0; mt < 4; mt++) {
        int row = wm + mt * 16 + l16;
        int s   = m0 + row;
        #pragma unroll
        for (int nt = 0; nt < 4; nt++) {
            int nl = wn + nt * 16 + quad * 4;
            int t0 = n0 + nl;
            ushortx4 pk;
            #pragma unroll
            for (int r = 0; r < 4; r++) {
                float z = (acc[mt][nt][r] + wbias[t0 + r - s + (S_LEN - 1)]) * 0.08838834764831845f;
                z = fmaxf(z, 0.f);
                pk[r] = f2bf(z * z);
            }
            *(uintx2*)&lds.T[swz(row, nl)] = *(uintx2*)&pk;
        }
    }
    __syncthreads();
    #pragma unroll
    for (int i = 0; i < 8; i++) {
        int idx = tid + i * 256;
        int row = idx >> 4;
        int j   = idx & 15;
        *(uintx4*)(Pb + (size_t)(m0 + row) * S_LEN + n0 + j * 8) =
            *(const uintx4*)&lds.T[swz(row, j * 8)];
    }
}

// ---------------------------------------------------------------------------
// PV: u <- u .* (P @ v), SWAPPED; swizzled transpose; coalesced b128 update
// 2048 blocks (xcd-remapped: 8 whole batches per XCD; P+vT batch = 1.5 MB)
// ---------------------------------------------------------------------------
__global__ __launch_bounds__(256) void gemm_pv_kernel(const unsigned short* __restrict__ P,
                                                      const unsigned short* __restrict__ vT,
                                                      unsigned short* __restrict__ u) {
    __shared__ LdsU lds;
    floatx4 acc[4][4];
    const int bl = (blockIdx.z * 8 + blockIdx.y) * 4 + blockIdx.x;
    const int lg = xcd_remap(bl, 2048);
    const int bx = lg & 3, by = (lg >> 2) & 7, bb = lg >> 5;
    const unsigned short* Pb  = P  + (size_t)bb * S_LEN * S_LEN;
    const unsigned short* vTb = vT + (size_t)bb * E_DIMC * S_LEN;
    const int m0 = bx * 128, n0 = by * 128;
    gemm_bt_core<true>(Pb, vTb, S_LEN, S_LEN, S_LEN, m0, n0, lds.g, acc);

    const int tid = threadIdx.x, lane = tid & 63, wave = tid >> 6;
    const int quad = lane >> 4, l16 = lane & 15;
    const int wm = (wave >> 1) * 64, wn = (wave & 1) * 64;
    #pragma unroll
    for (int mt = 0; mt < 4; mt++) {
        int row = wm + mt * 16 + l16;
        #pragma unroll
        for (int nt = 0; nt < 4; nt++) {
            int nl = wn + nt * 16 + quad * 4;
            ushortx4 pk;
            #pragma unroll
            for (int r = 0; r < 4; r++) pk[r] = f2bf(acc[mt][nt][r]);
            *(uintx2*)&lds.T[swz(row, nl)] = *(uintx2*)&pk;
        }
    }
    __syncthreads();
    #pragma unroll
    for (int i = 0; i < 8; i++) {
        int idx = tid + i * 256;
        int row = idx >> 4;
        int j   = idx & 15;
        size_t off = ((size_t)bb * S_LEN + m0 + row) * E_DIMC + n0 + j * 8;
        union { uintx4 u4; unsigned short s[8]; } tv, uv, ov;
        tv.u4 = *(const uintx4*)&lds.T[swz(row, j * 8)];
        uv.u4 = *(const uintx4*)(u + off);
        #pragma unroll
        for (int jj = 0; jj < 8; jj++) ov.s[jj] = f2bf(bf2f(tv.s[jj]) * bf2f(uv.s[jj]));
        *(uintx4*)(u + off) = ov.u4;
    }
}

// ---------------------------------------------------------------------------
extern "C" void kernel_launch(void* const* d_in, const int* in_sizes, int n_in,
                              void* d_out, int out_size, void* d_ws, size_t ws_size,
                              hipStream_t stream) {
    const float* x     = (const float*)d_in[0];
    const float* ln_g  = (const float*)d_in[1];
    const float* uv_w  = (const float*)d_in[2];
    const float* uv_b  = (const float*)d_in[3];
    const float* gamma = (const float*)d_in[4];
    const float* beta  = (const float*)d_in[5];
    const float* wbias = (const float*)d_in[6];
    const float* o_w   = (const float*)d_in[7];
    const float* o_b   = (const float*)d_in[8];
    float* out = (float*)d_out;

    char* ws = (char*)d_ws;
    size_t off = 0;
    auto alloc = [&](size_t bytes) {
        void* p = ws + off;
        off += (bytes + 255) & ~(size_t)255;
        return p;
    };
    // Peak ~196.5 MiB:
    unsigned short* u     = (unsigned short*)alloc((size_t)M_TOT * E_DIMC * 2);      // 64 MiB (u, then oe in place)
    unsigned short* vT    = (unsigned short*)alloc((size_t)64 * E_DIMC * S_LEN * 2); // 64 MiB
    unsigned short* xn    = (unsigned short*)alloc((size_t)M_TOT * H_DIM * 2);       // 32 MiB
    unsigned short* P     = xn;                                                      // alias (xn dead after gemm1)
    float*          base  = (float*)alloc((size_t)M_TOT * D_DIM * 4);                // 16 MiB
    unsigned short* q     = (unsigned short*)alloc((size_t)M_TOT * D_DIM * 2);       // 8 MiB
    unsigned short* k     = (unsigned short*)alloc((size_t)M_TOT * D_DIM * 2);       // 8 MiB
    float*          cost  = (float*)alloc((size_t)S_LEN * 64 * 4);
    float*          sint  = (float*)alloc((size_t)S_LEN * 64 * 4);
    unsigned short* uvwb  = (unsigned short*)alloc((size_t)UV_PAD * H_DIM * 2);      // 2.25 MiB (zero-padded)
    unsigned short* owb   = (unsigned short*)alloc((size_t)H_DIM * E_DIMC * 2);      // 1 MiB
    (void)ws_size; (void)in_sizes; (void)n_in; (void)out_size;

    f2bf_pad_kernel<<<(UV_PAD * H_DIM / 4 + 255) / 256, 256, 0, stream>>>(
        uv_w, uvwb, UV_DIM * H_DIM / 4, UV_PAD * H_DIM / 4);
    f2bf_kernel<<<(H_DIM * E_DIMC / 4 + 255) / 256, 256, 0, stream>>>(o_w, owb, H_DIM * E_DIMC / 4);
    rope_table_kernel<<<S_LEN, 64, 0, stream>>>(cost, sint);

    rmsnorm_kernel<<<M_TOT / 4, 256, 0, stream>>>(x, ln_g, xn);

    // gemm1 + silu (merged, 128x256 pipelined, r4-best): u / vT / base
    gemm1_128_kernel<<<dim3(9, M_TOT / 128), 512, 0, stream>>>(xn, uvwb, uv_b, u, vT, base);

    rope_apply_kernel<<<M_TOT * 64 / 256, 256, 0, stream>>>(base, gamma, beta, cost, sint, q, k);

    // P = relu^2((q k^T + bias)/sqrt(128))   (overwrites xn region)
    gemm_qk_kernel<<<dim3(S_LEN / 128, S_LEN / 128, 64), 256, 0, stream>>>(q, k, wbias, P);

    // u <- u .* (P @ v)  in place (old core, r3-best)
    gemm_pv_kernel<<<dim3(S_LEN / 128, E_DIMC / 128, 64), 256, 0, stream>>>(P, vT, u);

    // out = oe @ o_w^T + o_b + x (256^2 pipelined, r3-best)
    gemm_out256_kernel<<<dim3(H_DIM / 256, M_TOT / 256), 512, 0, stream>>>(u, owb, o_b, x, out);
}

// Round 7
// 354.676 us; speedup vs baseline: 1.1117x; 1.0084x over previous
//
#include <hip/hip_runtime.h>
#include <math.h>

// ---------------------------------------------------------------------------
// GAU-alpha fused block for MI355X (gfx950).
// B=64, S=512, H=512, E=1024, UV=2176, D=128, M=B*S=32768.
// bf16 MFMA (16x16x32) all matmuls; fp32 elsewhere.
// Round 14: r6 config frozen (best total 357.6us). This round removes pure
// overhead: (1) RoPE fused into gemm1's base epilogue via a 64KB LDS tile
// (base buffer + rope_apply kernel eliminated: -48MB traffic round-trip);
// (2) all prep elementwise (rmsnorm, uvw/o_w f2bf, rope tables) merged into
// one kernel (launches 7 -> 5).
//  - gemm1: r4 core: 128x256, BK=32, 3 bufs (72 KiB), depth-2, vmcnt(3)
//  - out  : r3 core: 256x256, BK=32, 4 bufs (128 KiB), depth-3, vmcnt(8), 1/CU
//  - pv,qk: old 128^2 drain core (r3 config)
// XCD chunked-bijective remap on all GEMM grids (r3: FETCH 180->65 MB).
// ---------------------------------------------------------------------------

#define M_TOT   32768
#define S_LEN   512
#define H_DIM   512
#define E_DIMC  1024
#define UV_DIM  2176
#define UV_PAD  2304   // padded so the 256-wide base tile reads zeros
#define D_DIM   128

using floatx4  = __attribute__((ext_vector_type(4))) float;
using uintx2   = __attribute__((ext_vector_type(2))) unsigned int;
using uintx4   = __attribute__((ext_vector_type(4))) unsigned int;
using ushortx4 = __attribute__((ext_vector_type(4))) unsigned short;
using short8   = __attribute__((ext_vector_type(8))) short;

#define ASYNC_CP16(gsrc, ldst)                                                  \
    __builtin_amdgcn_global_load_lds(                                           \
        (const __attribute__((address_space(1))) void*)(gsrc),                  \
        (__attribute__((address_space(3))) void*)(ldst), 16, 0, 0)

__device__ __forceinline__ float bf2f(unsigned short h) {
    union { unsigned int u; float f; } c;
    c.u = ((unsigned int)h) << 16;
    return c.f;
}
__device__ __forceinline__ unsigned short f2bf(float f) {
    union { float f; unsigned int u; } c;
    c.f = f;
    unsigned int r = c.u + 0x7fffu + ((c.u >> 16) & 1u);  // RNE
    return (unsigned short)(r >> 16);
}
__device__ __forceinline__ float silu_fast(float x) {
    float e = __expf(-x);                       // v_exp_f32
    return x * __builtin_amdgcn_rcpf(1.0f + e); // v_rcp_f32
}
// Chunked-bijective XCD remap: hw block b runs on XCD (b%8); give each XCD a
// CONTIGUOUS range of logical tiles so panel-sharing neighbors co-reside in
// one L2. Requires nwg % 8 == 0 (all our grids satisfy this).
__device__ __forceinline__ int xcd_remap(int b, int nwg) {
    return (b & 7) * (nwg >> 3) + (b >> 3);
}

// ---------------------------------------------------------------------------
// PREP (merged): rmsnorm (blocks 0..8191), uvw pad-convert (8192..9343),
// o_w convert (9344..9855), rope tables (9856..9983). All independent.
// ---------------------------------------------------------------------------
__global__ __launch_bounds__(256) void prep_kernel(const float* __restrict__ x,
                                                   const float* __restrict__ ln_g,
                                                   unsigned short* __restrict__ xn,
                                                   const float* __restrict__ uv_w,
                                                   unsigned short* __restrict__ uvwb,
                                                   const float* __restrict__ o_w,
                                                   unsigned short* __restrict__ owb,
                                                   float* __restrict__ cost,
                                                   float* __restrict__ sint) {
    const int bid = blockIdx.x;
    const int tid = threadIdx.x;
    if (bid < 8192) {
        // rmsnorm: 4 rows per block
        int row  = bid * 4 + (tid >> 6);
        int lane = tid & 63;
        const float* xr = x + (size_t)row * H_DIM;
        floatx4 v0 = ((const floatx4*)xr)[lane];
        floatx4 v1 = ((const floatx4*)xr)[lane + 64];
        float ss = v0.x*v0.x + v0.y*v0.y + v0.z*v0.z + v0.w*v0.w
                 + v1.x*v1.x + v1.y*v1.y + v1.z*v1.z + v1.w*v1.w;
        #pragma unroll
        for (int off = 32; off > 0; off >>= 1) ss += __shfl_xor(ss, off, 64);
        float norm = sqrtf(ss) * 0.044194173824159216f;  // * H^-0.5
        float sc   = ln_g[0] / fmaxf(norm, 1e-5f);
        unsigned short* xo = xn + (size_t)row * H_DIM;
        ushortx4 o0, o1;
        o0.x = f2bf(v0.x * sc); o0.y = f2bf(v0.y * sc);
        o0.z = f2bf(v0.z * sc); o0.w = f2bf(v0.w * sc);
        o1.x = f2bf(v1.x * sc); o1.y = f2bf(v1.y * sc);
        o1.z = f2bf(v1.z * sc); o1.w = f2bf(v1.w * sc);
        ((ushortx4*)xo)[lane]      = o0;
        ((ushortx4*)xo)[lane + 64] = o1;
    } else if (bid < 9344) {
        // uvw f2bf with zero pad: n4_src = 278528, n4_dst = 294912
        int i = (bid - 8192) * 256 + tid;
        ushortx4 o;
        if (i < UV_DIM * H_DIM / 4) {
            floatx4 v = ((const floatx4*)uv_w)[i];
            o.x = f2bf(v.x); o.y = f2bf(v.y); o.z = f2bf(v.z); o.w = f2bf(v.w);
        } else {
            o.x = 0; o.y = 0; o.z = 0; o.w = 0;
        }
        ((ushortx4*)uvwb)[i] = o;
    } else if (bid < 9856) {
        // o_w f2bf: exactly 512*256 = 131072 float4s
        int i = (bid - 9344) * 256 + tid;
        floatx4 v = ((const floatx4*)o_w)[i];
        ushortx4 o;
        o.x = f2bf(v.x); o.y = f2bf(v.y); o.z = f2bf(v.z); o.w = f2bf(v.w);
        ((ushortx4*)owb)[i] = o;
    } else {
        // rope tables: 128 blocks * 256 = 32768 = 512 s * 64 j
        int idx = (bid - 9856) * 256 + tid;
        int s = idx >> 6;
        int j = idx & 63;
        float invf = (float)pow(10000.0, (double)j / 64.0);
        float ang  = (float)s * invf;  // fp32 multiply like the f32 reference
        double a   = (double)ang;
        cost[s * 64 + j] = (float)cos(a);
        sint[s * 64 + j] = (float)sin(a);
    }
}

// ===========================================================================
// 128x256 pipelined GEMM core (r4-proven): 8 waves (2M x 4N),
// per-wave C = 64x64 (acc[4][4]). BK=32. 3 LDS bufs of 24 KiB = 72 KiB.
// Depth-2 prefetch, counted vmcnt(3) (0 only at final tile), 1 s_barrier per
// K-tile, setprio(1) around MFMA cluster, sched_barrier(0) pins.
// LDS packing (per buf): two logical rows per 128B LDS row, XOR swizzle:
//   R = row>>1; c = (row&1)*4 + (k>>3); phys cp = c^(R&7).
// Staging LDS-linear (gload_lds), inverse swizzle on global source.
// Race-freedom: stage(t+2) overwrites buf[(t-1)%3], whose reads retired
// before the tile-t barrier; vmcnt(3) at entry = tile-t loads landed.
// ===========================================================================
template <bool SWAPT>
__device__ __forceinline__ void gemm128_core(const unsigned short* __restrict__ A,
                                             const unsigned short* __restrict__ B,
                                             int lda, int ldb, int K,
                                             int m0, int n0,
                                             unsigned short (&st)[3][12288],
                                             floatx4 (&acc)[4][4]) {
    const int tid  = threadIdx.x;
    const int lane = tid & 63;
    const int wave = tid >> 6;
    const int quad = lane >> 4;
    const int l16  = lane & 15;
    const int wrow = (wave >> 2) * 64;
    const int wcol = (wave & 3) * 64;

    const int qa  = wave * 64 + lane;
    const int Ra  = qa >> 3;
    const int ca  = (qa & 7) ^ (Ra & 7);      // inverse swizzle
    const int srA = 2 * Ra + (ca >> 2);       // logical row 0..127
    const int scA = (ca & 3) * 8;             // k offset (shorts)
    const unsigned short* pa  = A + (size_t)(m0 + srA) * lda + scA;
    const unsigned short* pb0 = B + (size_t)(n0 + srA) * ldb + scA;
    const unsigned short* pb1 = pb0 + (size_t)128 * ldb;   // B rows 128..255
    const int ldsA  = (wave * 64) * 8;
    const int ldsB0 = 4096 + (wave * 64) * 8;
    const int ldsB1 = 4096 + (512 + wave * 64) * 8;

    #pragma unroll
    for (int i = 0; i < 4; i++)
        #pragma unroll
        for (int j = 0; j < 4; j++) acc[i][j] = (floatx4){0.f, 0.f, 0.f, 0.f};

    const int NT = K >> 5;
    auto stage = [&](int buf, int t) {
        unsigned short* s = &st[buf][0];
        const int kt = t * 32;
        ASYNC_CP16(pa  + kt, s + ldsA);
        ASYNC_CP16(pb0 + kt, s + ldsB0);
        ASYNC_CP16(pb1 + kt, s + ldsB1);
    };
    stage(0, 0);
    stage(1, 1);

    int aoff[4], boff[4];
    #pragma unroll
    for (int mt = 0; mt < 4; mt++) {
        int r  = wrow + mt * 16 + l16;        // 0..127
        int Rr = r >> 1;
        int cp = (((r & 1) << 2) + quad) ^ (Rr & 7);
        aoff[mt] = Rr * 64 + cp * 8;
    }
    #pragma unroll
    for (int nt = 0; nt < 4; nt++) {
        int r  = wcol + nt * 16 + l16;        // 0..255
        int Rr = r >> 1;
        int cp = (((r & 1) << 2) + quad) ^ (Rr & 7);
        boff[nt] = 4096 + Rr * 64 + cp * 8;
    }

    int bc = 0, bs = 2;
    for (int t = 0; t < NT; ++t) {
        if (t < NT - 1) asm volatile("s_waitcnt vmcnt(3)" ::: "memory");
        else            asm volatile("s_waitcnt vmcnt(0)" ::: "memory");
        __builtin_amdgcn_sched_barrier(0);   // pin: nothing crosses the wait
        __builtin_amdgcn_s_barrier();
        __builtin_amdgcn_sched_barrier(0);   // pin: ds_reads stay below barrier
        if (t + 2 < NT) stage(bs, t + 2);

        const unsigned short* sb = &st[bc][0];
        short8 af[4], bf[4];
        #pragma unroll
        for (int mt = 0; mt < 4; mt++) {
            union { short8 s8; uintx4 u4; } fu;
            fu.u4 = *(const uintx4*)&sb[aoff[mt]];
            af[mt] = fu.s8;
        }
        #pragma unroll
        for (int nt = 0; nt < 4; nt++) {
            union { short8 s8; uintx4 u4; } fu;
            fu.u4 = *(const uintx4*)&sb[boff[nt]];
            bf[nt] = fu.s8;
        }
        __builtin_amdgcn_s_setprio(1);
        #pragma unroll
        for (int mt = 0; mt < 4; mt++)
            #pragma unroll
            for (int nt = 0; nt < 4; nt++)
                acc[mt][nt] = SWAPT
                    ? __builtin_amdgcn_mfma_f32_16x16x32_bf16(bf[nt], af[mt], acc[mt][nt], 0, 0, 0)
                    : __builtin_amdgcn_mfma_f32_16x16x32_bf16(af[mt], bf[nt], acc[mt][nt], 0, 0, 0);
        __builtin_amdgcn_s_setprio(0);

        bc = (bc == 2) ? 0 : bc + 1;
        bs = (bs == 2) ? 0 : bs + 1;
    }
}

// LDS: staging (72 KiB) unioned with the epilogue transpose tile (64 KiB)
// and the fp32 RoPE tile Tf[128][132] (66 KiB, stride-132 anti-conflict).
union __align__(16) Lds3 {
    unsigned short st[3][12288];   // 73728 B staging
    unsigned short T[128 * 256];   // 65536 B epilogue
    float          Tf[128][132];   // 67584 B rope tile
};

// ---------------------------------------------------------------------------
// GEMM1 (merged): act = silu(xn @ uv_w^T + uv_b), grid (9, 256) xcd-remapped
//   xb <  4 : u columns, SWAPPED, swizzled LDS transpose, b128 stores
//   xb 4..7 : v columns, UNSWAPPED, T[n][m] transpose -> vT (b,e,s)
//   xb == 8 : base columns, UNSWAPPED, + FUSED ROPE -> q,k direct (no base buf)
// ---------------------------------------------------------------------------
__global__ __launch_bounds__(512, 2) void gemm1_128_kernel(const unsigned short* __restrict__ xn,
                                                           const unsigned short* __restrict__ uvw,
                                                           const float* __restrict__ uvb,
                                                           unsigned short* __restrict__ u,
                                                           unsigned short* __restrict__ vT,
                                                           const float* __restrict__ gamma,
                                                           const float* __restrict__ beta,
                                                           const float* __restrict__ cost,
                                                           const float* __restrict__ sint,
                                                           unsigned short* __restrict__ q,
                                                           unsigned short* __restrict__ k) {
    __shared__ Lds3 lds;
    floatx4 acc[4][4];
    const int bl = blockIdx.y * 9 + blockIdx.x;
    const int lg = xcd_remap(bl, 9 * (M_TOT / 128));  // 2304
    const int xb = lg % 9;
    const int m0 = (lg / 9) * 128;
    const int tid = threadIdx.x, lane = tid & 63, wave = tid >> 6;
    const int quad = lane >> 4, l16 = lane & 15;
    const int wrow = (wave >> 2) * 64, wcol = (wave & 3) * 64;

    if (xb < 4) {
        const int n0 = xb * 256;
        gemm128_core<true>(xn, uvw, H_DIM, H_DIM, H_DIM, m0, n0, lds.st, acc);
        __syncthreads();
        #pragma unroll
        for (int mt = 0; mt < 4; mt++) {
            int row = wrow + mt * 16 + l16;           // 0..127
            #pragma unroll
            for (int nt = 0; nt < 4; nt++) {
                int nl = wcol + nt * 16 + quad * 4;   // 0..255
                floatx4 b4 = *(const floatx4*)&uvb[n0 + nl];
                ushortx4 pk;
                #pragma unroll
                for (int r = 0; r < 4; r++)
                    pk[r] = f2bf(silu_fast(acc[mt][nt][r] + b4[r]));
                *(uintx2*)&lds.T[row * 256 + (((nl >> 3) ^ (row & 15)) << 3) + (nl & 7)] = *(uintx2*)&pk;
            }
        }
        __syncthreads();
        #pragma unroll
        for (int i = 0; i < 8; i++) {
            int idx = tid + i * 512;                  // 0..4095
            int row = idx >> 5, c16 = idx & 31;
            *(uintx4*)(u + (size_t)(m0 + row) * E_DIMC + n0 + c16 * 8) =
                *(const uintx4*)&lds.T[row * 256 + ((c16 ^ (row & 15)) << 3)];
        }
    } else if (xb < 8) {
        const int n0 = xb * 256;  // 1024..1792 in act space
        gemm128_core<false>(xn, uvw, H_DIM, H_DIM, H_DIM, m0, n0, lds.st, acc);
        __syncthreads();
        #pragma unroll
        for (int nt = 0; nt < 4; nt++) {
            int rowT = wcol + nt * 16 + l16;          // n-local 0..255
            float bias = uvb[n0 + rowT];
            #pragma unroll
            for (int mt = 0; mt < 4; mt++) {
                int colT = wrow + mt * 16 + quad * 4; // m-local 0..127
                ushortx4 pk;
                #pragma unroll
                for (int r = 0; r < 4; r++)
                    pk[r] = f2bf(silu_fast(acc[mt][nt][r] + bias));
                *(uintx2*)&lds.T[rowT * 128 + (((colT >> 3) ^ (rowT & 15)) << 3) + (colT & 7)] = *(uintx2*)&pk;
            }
        }
        __syncthreads();
        const int b = m0 >> 9, sg0 = m0 & (S_LEN - 1), eg0 = n0 - E_DIMC;
        #pragma unroll
        for (int i = 0; i < 8; i++) {
            int idx = tid + i * 512;                  // 0..4095
            int e = idx >> 4, j = idx & 15;
            *(uintx4*)(vT + ((size_t)b * E_DIMC + eg0 + e) * S_LEN + sg0 + j * 8) =
                *(const uintx4*)&lds.T[e * 128 + ((j ^ (e & 15)) << 3)];
        }
    } else {
        const int n0 = 2048;  // base slice; cols 128..255 hit zero-padded uvw
        gemm128_core<false>(xn, uvw, H_DIM, H_DIM, H_DIM, m0, n0, lds.st, acc);
        __syncthreads();   // staging LDS dead; safe to overwrite with Tf
        if ((wave & 3) < 2) {
            #pragma unroll
            for (int mt = 0; mt < 4; mt++) {
                int rowl = wrow + mt * 16 + quad * 4;     // 0..127 (rows rowl..+3)
                #pragma unroll
                for (int nt = 0; nt < 4; nt++) {
                    int n = wcol + nt * 16 + l16;         // 0..127
                    float bias = uvb[2048 + n];
                    #pragma unroll
                    for (int r = 0; r < 4; r++)
                        lds.Tf[rowl + r][n] = silu_fast(acc[mt][nt][r] + bias);
                }
            }
        }
        __syncthreads();
        // fused RoPE: 128 rows x 64 j pairs = 8192 items, 16 per thread
        #pragma unroll
        for (int i = 0; i < 16; i++) {
            int idx = tid + i * 512;         // 0..8191
            int row = idx >> 6, j = idx & 63;
            int s   = (m0 + row) & (S_LEN - 1);
            float b1 = lds.Tf[row][j];
            float b2 = lds.Tf[row][j + 64];
            float c  = cost[s * 64 + j];
            float sn = sint[s * 64 + j];
            float yq1 = b1 * gamma[j]       + beta[j];
            float yq2 = b2 * gamma[64 + j]  + beta[64 + j];
            float yk1 = b1 * gamma[128 + j] + beta[128 + j];
            float yk2 = b2 * gamma[192 + j] + beta[192 + j];
            size_t mo = (size_t)(m0 + row) * D_DIM;
            q[mo + j]      = f2bf(yq1 * c - yq2 * sn);
            q[mo + 64 + j] = f2bf(yq2 * c + yq1 * sn);
            k[mo + j]      = f2bf(yk1 * c - yk2 * sn);
            k[mo + 64 + j] = f2bf(yk2 * c + yk1 * sn);
        }
    }
}

// ===========================================================================
// 256x256 pipelined GEMM core (r3-proven, best gemm_out): 8 waves (2M x 4N),
// per-wave C = 128x64 (acc[8][4]). BK=32. 4 LDS bufs (128 KiB), depth-3
// prefetch, counted vmcnt(8)/(4)/(0) tail, 1 s_barrier per K-tile,
// setprio(1) around MFMA clusters, sched_barrier(0) pins.
// ===========================================================================
template <bool SWAPT>
__device__ __forceinline__ void gemm256_core(const unsigned short* __restrict__ A,
                                             const unsigned short* __restrict__ B,
                                             int lda, int ldb, int K,
                                             int m0, int n0,
                                             unsigned short (&st)[4][2][128][64],
                                             floatx4 (&acc)[8][4]) {
    const int tid  = threadIdx.x;
    const int lane = tid & 63;
    const int wave = tid >> 6;
    const int quad = lane >> 4;
    const int l16  = lane & 15;
    const int wrow = (wave >> 2) * 128;
    const int wcol = (wave & 3) * 64;

    const int q0    = wave * 128 + lane;        // linear 16B chunk, i=0
    const int R0    = q0 >> 3;                  // LDS row (i=1: +8)
    const int cp0   = q0 & 7;                   // physical chunk in row
    const int c0    = cp0 ^ (R0 & 7);           // logical chunk (inverse swz)
    const int srow0 = 2 * R0 + (c0 >> 2);       // logical tile row (i=1: +16)
    const int scol0 = (c0 & 3) * 8;             // k-offset in shorts

    const unsigned short* pa0 = A + (size_t)(m0 + srow0) * lda + scol0;
    const unsigned short* pa1 = pa0 + (size_t)16 * lda;
    const unsigned short* pb0 = B + (size_t)(n0 + srow0) * ldb + scol0;
    const unsigned short* pb1 = pb0 + (size_t)16 * ldb;
    const int ldsOff0 = (wave * 128) * 8;       // ushort index of uniform base
    const int ldsOff1 = (wave * 128 + 64) * 8;

    #pragma unroll
    for (int i = 0; i < 8; i++)
        #pragma unroll
        for (int j = 0; j < 4; j++) acc[i][j] = (floatx4){0.f, 0.f, 0.f, 0.f};

    const int NT = K >> 5;
    auto stage = [&](int t) {
        unsigned short* sA = &st[t & 3][0][0][0];
        unsigned short* sB = &st[t & 3][1][0][0];
        const int kt = t * 32;
        ASYNC_CP16(pa0 + kt, sA + ldsOff0);
        ASYNC_CP16(pa1 + kt, sA + ldsOff1);
        ASYNC_CP16(pb0 + kt, sB + ldsOff0);
        ASYNC_CP16(pb1 + kt, sB + ldsOff1);
    };
    stage(0);
    stage(1);
    stage(2);

    int aoff[8], boff[4];
    #pragma unroll
    for (int mt = 0; mt < 8; mt++) {
        int r  = wrow + mt * 16 + l16;
        int Rr = r >> 1;
        int cp = (((r & 1) << 2) + quad) ^ (Rr & 7);
        aoff[mt] = Rr * 64 + cp * 8;
    }
    #pragma unroll
    for (int nt = 0; nt < 4; nt++) {
        int r  = wcol + nt * 16 + l16;
        int Rr = r >> 1;
        int cp = (((r & 1) << 2) + quad) ^ (Rr & 7);
        boff[nt] = Rr * 64 + cp * 8;
    }

    for (int t = 0; t < NT; ++t) {
        if (t < NT - 2)       asm volatile("s_waitcnt vmcnt(8)" ::: "memory");
        else if (t == NT - 2) asm volatile("s_waitcnt vmcnt(4)" ::: "memory");
        else                  asm volatile("s_waitcnt vmcnt(0)" ::: "memory");
        __builtin_amdgcn_sched_barrier(0);
        __builtin_amdgcn_s_barrier();
        __builtin_amdgcn_sched_barrier(0);
        if (t + 3 < NT) stage(t + 3);

        const unsigned short* sA = &st[t & 3][0][0][0];
        const unsigned short* sB = &st[t & 3][1][0][0];
        short8 bf[4];
        #pragma unroll
        for (int nt = 0; nt < 4; nt++) {
            union { short8 s8; uintx4 u4; } fu;
            fu.u4 = *(const uintx4*)&sB[boff[nt]];
            bf[nt] = fu.s8;
        }
        #pragma unroll
        for (int half = 0; half < 2; half++) {
            short8 af[4];
            #pragma unroll
            for (int mt = 0; mt < 4; mt++) {
                union { short8 s8; uintx4 u4; } fu;
                fu.u4 = *(const uintx4*)&sA[aoff[half * 4 + mt]];
                af[mt] = fu.s8;
            }
            __builtin_amdgcn_s_setprio(1);
            #pragma unroll
            for (int mt = 0; mt < 4; mt++)
                #pragma unroll
                for (int nt = 0; nt < 4; nt++)
                    acc[half * 4 + mt][nt] = SWAPT
                        ? __builtin_amdgcn_mfma_f32_16x16x32_bf16(bf[nt], af[mt], acc[half * 4 + mt][nt], 0, 0, 0)
                        : __builtin_amdgcn_mfma_f32_16x16x32_bf16(af[mt], bf[nt], acc[half * 4 + mt][nt], 0, 0, 0);
            __builtin_amdgcn_s_setprio(0);
        }
    }
}

// ---------------------------------------------------------------------------
// OUT: out = oe @ o_w^T + o_b + x, 256^2 pipelined core, direct f32 stores.
// 256 blocks (xcd-remapped: each XCD owns 16 m-panels; ow 1 MB L2-resident).
// ---------------------------------------------------------------------------
__global__ __launch_bounds__(512, 2) void gemm_out256_kernel(const unsigned short* __restrict__ oe,
                                                             const unsigned short* __restrict__ ow,
                                                             const float* __restrict__ ob,
                                                             const float* __restrict__ x,
                                                             float* __restrict__ out) {
    __shared__ __align__(16) unsigned short st[4][2][128][64];
    floatx4 acc[8][4];
    const int bl = blockIdx.y * 2 + blockIdx.x;
    const int lg = xcd_remap(bl, 2 * (M_TOT / 256)); // 256
    const int n0 = (lg & 1) * 256;
    const int m0 = (lg >> 1) * 256;
    gemm256_core<true>(oe, ow, E_DIMC, E_DIMC, E_DIMC, m0, n0, st, acc);

    const int tid = threadIdx.x, lane = tid & 63, wave = tid >> 6;
    const int quad = lane >> 4, l16 = lane & 15;
    const int wrow = (wave >> 2) * 128, wcol = (wave & 3) * 64;
    #pragma unroll
    for (int mt = 0; mt < 8; mt++) {
        int m = m0 + wrow + mt * 16 + l16;
        #pragma unroll
        for (int nt = 0; nt < 4; nt++) {
            int n = n0 + wcol + nt * 16 + quad * 4;
            size_t off = (size_t)m * H_DIM + n;
            floatx4 b4 = *(const floatx4*)&ob[n];
            floatx4 x4 = *(const floatx4*)&x[off];
            *(floatx4*)&out[off] = acc[mt][nt] + b4 + x4;
        }
    }
}

// ===========================================================================
// OLD 128x128 drain core (kept for qk / pv — r3-measured best for both)
// ===========================================================================
struct GemmLds {
    unsigned short As[128 * 64];
    unsigned short Bs[128 * 64];
};

template <bool SWAPT>
__device__ __forceinline__ void gemm_bt_core(const unsigned short* __restrict__ A,
                                             const unsigned short* __restrict__ B,
                                             int lda, int ldb, int K,
                                             int m0, int n0,
                                             GemmLds& lds, floatx4 (&acc)[4][4]) {
    const int tid  = threadIdx.x;
    const int lane = tid & 63;
    const int wave = tid >> 6;
    const int quad = lane >> 4;
    const int l16  = lane & 15;
    const int wm   = (wave >> 1) * 64;
    const int wn   = (wave & 1) * 64;
    const int lrow = lane >> 3;                    // 0..7
    const int cgs  = ((lane & 7) ^ lrow) * 8;      // swizzled source col (shorts)

    #pragma unroll
    for (int i = 0; i < 4; i++)
        #pragma unroll
        for (int j = 0; j < 4; j++) acc[i][j] = (floatx4){0.f, 0.f, 0.f, 0.f};

    for (int kt = 0; kt < K; kt += 64) {
        #pragma unroll
        for (int i = 0; i < 4; i++) {
            int r0 = wave * 32 + i * 8;
            const unsigned short* ga = A + (size_t)(m0 + r0 + lrow) * lda + kt + cgs;
            const unsigned short* gb = B + (size_t)(n0 + r0 + lrow) * ldb + kt + cgs;
            ASYNC_CP16(ga, &lds.As[r0 * 64]);
            ASYNC_CP16(gb, &lds.Bs[r0 * 64]);
        }
        __syncthreads();
        #pragma unroll
        for (int kk = 0; kk < 64; kk += 32) {
            short8 af[4], bf[4];
            const int pc = (kk + quad * 8) ^ ((l16 & 7) * 8);  // physical col
            #pragma unroll
            for (int mt = 0; mt < 4; mt++) {
                int row = wm + mt * 16 + l16;
                union { short8 s8; uintx4 u4; } fu;
                fu.u4 = *(const uintx4*)&lds.As[row * 64 + pc];
                af[mt] = fu.s8;
            }
            #pragma unroll
            for (int nt = 0; nt < 4; nt++) {
                int row = wn + nt * 16 + l16;
                union { short8 s8; uintx4 u4; } fu;
                fu.u4 = *(const uintx4*)&lds.Bs[row * 64 + pc];
                bf[nt] = fu.s8;
            }
            #pragma unroll
            for (int mt = 0; mt < 4; mt++)
                #pragma unroll
                for (int nt = 0; nt < 4; nt++)
                    acc[mt][nt] = SWAPT
                        ? __builtin_amdgcn_mfma_f32_16x16x32_bf16(bf[nt], af[mt], acc[mt][nt], 0, 0, 0)
                        : __builtin_amdgcn_mfma_f32_16x16x32_bf16(af[mt], bf[nt], acc[mt][nt], 0, 0, 0);
        }
        __syncthreads();
    }
}

union LdsU {
    GemmLds g;
    unsigned short T[128 * 128];   // 32768 B == sizeof(GemmLds)
};
__device__ __forceinline__ int swz(int row, int col) {
    return row * 128 + ((((col >> 3) ^ (row & 7)) << 3) | (col & 7));
}

// ---------------------------------------------------------------------------
// qk: P = relu((q k^T + w_bias)/sqrt(128))^2, SWAPPED, swizzled LDS transpose
// 1024 blocks (xcd-remapped: 8 whole batches per XCD)
// ---------------------------------------------------------------------------
__global__ __launch_bounds__(256) void gemm_qk_kernel(const unsigned short* __restrict__ q,
                                                      const unsigned short* __restrict__ k,
                                                      const float* __restrict__ wbias,
                                                      unsigned short* __restrict__ P) {
    __shared__ LdsU lds;
    floatx4 acc[4][4];
    const int bl = (blockIdx.z * 4 + blockIdx.y) * 4 + blockIdx.x;
    const int lg = xcd_remap(bl, 1024);
    const int bx = lg & 3, by = (lg >> 2) & 3, bz = lg >> 4;
    size_t boff = (size_t)bz * S_LEN * D_DIM;
    unsigned short* Pb = P + (size_t)bz * S_LEN * S_LEN;
    const int m0 = bx * 128, n0 = by * 128;
    gemm_bt_core<true>(q + boff, k + boff, D_DIM, D_DIM, D_DIM, m0, n0, lds.g, acc);

    const int tid = threadIdx.x, lane = tid & 63, wave = tid >> 6;
    const int quad = lane >> 4, l16 = lane & 15;
    const int wm = (wave >> 1) * 64, wn = (wave & 1) * 64;
    #pragma unroll
    for (int mt = 0; mt < 4; mt++) {
        int row = wm + mt * 16 + l16;
        int s   = m0 + row;
        #pragma unroll
        for (int nt = 0; nt < 4; nt++) {
            int nl = wn + nt * 16 + quad * 4;
            int t0 = n0 + nl;
            ushortx4 pk;
            #pragma unroll
            for (int r = 0; r < 4; r++) {
                float z = (acc[mt][nt][r] + wbias[t0 + r - s + (S_LEN - 1)]) * 0.08838834764831845f;
                z = fmaxf(z, 0.f);
                pk[r] = f2bf(z * z);
            }
            *(uintx2*)&lds.T[swz(row, nl)] = *(uintx2*)&pk;
        }
    }
    __syncthreads();
    #pragma unroll
    for (int i = 0; i < 8; i++) {
        int idx = tid + i * 256;
        int row = idx >> 4;
        int j   = idx & 15;
        *(uintx4*)(Pb + (size_t)(m0 + row) * S_LEN + n0 + j * 8) =
            *(const uintx4*)&lds.T[swz(row, j * 8)];
    }
}

// ---------------------------------------------------------------------------
// PV: u <- u .* (P @ v), SWAPPED; swizzled transpose; coalesced b128 update
// 2048 blocks (xcd-remapped: 8 whole batches per XCD; P+vT batch = 1.5 MB)
// ---------------------------------------------------------------------------
__global__ __launch_bounds__(256) void gemm_pv_kernel(const unsigned short* __restrict__ P,
                                                      const unsigned short* __restrict__ vT,
                                                      unsigned short* __restrict__ u) {
    __shared__ LdsU lds;
    floatx4 acc[4][4];
    const int bl = (blockIdx.z * 8 + blockIdx.y) * 4 + blockIdx.x;
    const int lg = xcd_remap(bl, 2048);
    const int bx = lg & 3, by = (lg >> 2) & 7, bb = lg >> 5;
    const unsigned short* Pb  = P  + (size_t)bb * S_LEN * S_LEN;
    const unsigned short* vTb = vT + (size_t)bb * E_DIMC * S_LEN;
    const int m0 = bx * 128, n0 = by * 128;
    gemm_bt_core<true>(Pb, vTb, S_LEN, S_LEN, S_LEN, m0, n0, lds.g, acc);

    const int tid = threadIdx.x, lane = tid & 63, wave = tid >> 6;
    const int quad = lane >> 4, l16 = lane & 15;
    const int wm = (wave >> 1) * 64, wn = (wave & 1) * 64;
    #pragma unroll
    for (int mt = 0; mt < 4; mt++) {
        int row = wm + mt * 16 + l16;
        #pragma unroll
        for (int nt = 0; nt < 4; nt++) {
            int nl = wn + nt * 16 + quad * 4;
            ushortx4 pk;
            #pragma unroll
            for (int r = 0; r < 4; r++) pk[r] = f2bf(acc[mt][nt][r]);
            *(uintx2*)&lds.T[swz(row, nl)] = *(uintx2*)&pk;
        }
    }
    __syncthreads();
    #pragma unroll
    for (int i = 0; i < 8; i++) {
        int idx = tid + i * 256;
        int row = idx >> 4;
        int j   = idx & 15;
        size_t off = ((size_t)bb * S_LEN + m0 + row) * E_DIMC + n0 + j * 8;
        union { uintx4 u4; unsigned short s[8]; } tv, uv, ov;
        tv.u4 = *(const uintx4*)&lds.T[swz(row, j * 8)];
        uv.u4 = *(const uintx4*)(u + off);
        #pragma unroll
        for (int jj = 0; jj < 8; jj++) ov.s[jj] = f2bf(bf2f(tv.s[jj]) * bf2f(uv.s[jj]));
        *(uintx4*)(u + off) = ov.u4;
    }
}

// ---------------------------------------------------------------------------
extern "C" void kernel_launch(void* const* d_in, const int* in_sizes, int n_in,
                              void* d_out, int out_size, void* d_ws, size_t ws_size,
                              hipStream_t stream) {
    const float* x     = (const float*)d_in[0];
    const float* ln_g  = (const float*)d_in[1];
    const float* uv_w  = (const float*)d_in[2];
    const float* uv_b  = (const float*)d_in[3];
    const float* gamma = (const float*)d_in[4];
    const float* beta  = (const float*)d_in[5];
    const float* wbias = (const float*)d_in[6];
    const float* o_w   = (const float*)d_in[7];
    const float* o_b   = (const float*)d_in[8];
    float* out = (float*)d_out;

    char* ws = (char*)d_ws;
    size_t off = 0;
    auto alloc = [&](size_t bytes) {
        void* p = ws + off;
        off += (bytes + 255) & ~(size_t)255;
        return p;
    };
    // Peak ~180 MiB:
    unsigned short* u     = (unsigned short*)alloc((size_t)M_TOT * E_DIMC * 2);      // 64 MiB (u, then oe in place)
    unsigned short* vT    = (unsigned short*)alloc((size_t)64 * E_DIMC * S_LEN * 2); // 64 MiB
    unsigned short* xn    = (unsigned short*)alloc((size_t)M_TOT * H_DIM * 2);       // 32 MiB
    unsigned short* P     = xn;                                                      // alias (xn dead after gemm1)
    unsigned short* q     = (unsigned short*)alloc((size_t)M_TOT * D_DIM * 2);       // 8 MiB
    unsigned short* k     = (unsigned short*)alloc((size_t)M_TOT * D_DIM * 2);       // 8 MiB
    float*          cost  = (float*)alloc((size_t)S_LEN * 64 * 4);
    float*          sint  = (float*)alloc((size_t)S_LEN * 64 * 4);
    unsigned short* uvwb  = (unsigned short*)alloc((size_t)UV_PAD * H_DIM * 2);      // 2.25 MiB (zero-padded)
    unsigned short* owb   = (unsigned short*)alloc((size_t)H_DIM * E_DIMC * 2);      // 1 MiB
    (void)ws_size; (void)in_sizes; (void)n_in; (void)out_size;

    // prep (merged): rmsnorm + uvw pad-convert + o_w convert + rope tables
    prep_kernel<<<9984, 256, 0, stream>>>(x, ln_g, xn, uv_w, uvwb, o_w, owb, cost, sint);

    // gemm1 + silu + fused rope (128x256 pipelined): u / vT / q,k
    gemm1_128_kernel<<<dim3(9, M_TOT / 128), 512, 0, stream>>>(
        xn, uvwb, uv_b, u, vT, gamma, beta, cost, sint, q, k);

    // P = relu^2((q k^T + bias)/sqrt(128))   (overwrites xn region)
    gemm_qk_kernel<<<dim3(S_LEN / 128, S_LEN / 128, 64), 256, 0, stream>>>(q, k, wbias, P);

    // u <- u .* (P @ v)  in place (old core, r3-best)
    gemm_pv_kernel<<<dim3(S_LEN / 128, E_DIMC / 128, 64), 256, 0, stream>>>(P, vT, u);

    // out = oe @ o_w^T + o_b + x (256^2 pipelined, r3-best)
    gemm_out256_kernel<<<dim3(H_DIM / 256, M_TOT / 256), 512, 0, stream>>>(u, owb, o_b, x, out);
}

// Round 8
// 345.142 us; speedup vs baseline: 1.1424x; 1.0276x over previous
//
#include <hip/hip_runtime.h>
#include <math.h>

// ---------------------------------------------------------------------------
// GAU-alpha fused block for MI355X (gfx950).
// B=64, S=512, H=512, E=1024, UV=2176, D=128, M=B*S=32768.
// bf16 MFMA (16x16x32) all matmuls; fp32 elsewhere.
// Round 15: move the last two drain-core kernels onto session-proven
// pipelined cores (no new sync structures):
//  - pv -> r3-proven 256^2 depth-3 core (vmcnt(8)) + r2-verified 256^2
//    swizzled-LDS transpose epilogue + coalesced b128 RMW of u. 512 blocks.
//  - qk -> r4-proven 128x256 depth-2 core (vmcnt(3)); K=128 = 4 pipelined
//    BK=32 tiles (old core: 2 full-drain BK=64 tiles). 512 blocks, 512 thr.
// gemm1 (117us, rope-fused), out256, prep: byte-identical to r7.
// XCD chunked-bijective remap everywhere (r3: FETCH 180->65 MB).
// ---------------------------------------------------------------------------

#define M_TOT   32768
#define S_LEN   512
#define H_DIM   512
#define E_DIMC  1024
#define UV_DIM  2176
#define UV_PAD  2304   // padded so the 256-wide base tile reads zeros
#define D_DIM   128

using floatx4  = __attribute__((ext_vector_type(4))) float;
using uintx2   = __attribute__((ext_vector_type(2))) unsigned int;
using uintx4   = __attribute__((ext_vector_type(4))) unsigned int;
using ushortx4 = __attribute__((ext_vector_type(4))) unsigned short;
using short8   = __attribute__((ext_vector_type(8))) short;

#define ASYNC_CP16(gsrc, ldst)                                                  \
    __builtin_amdgcn_global_load_lds(                                           \
        (const __attribute__((address_space(1))) void*)(gsrc),                  \
        (__attribute__((address_space(3))) void*)(ldst), 16, 0, 0)

__device__ __forceinline__ float bf2f(unsigned short h) {
    union { unsigned int u; float f; } c;
    c.u = ((unsigned int)h) << 16;
    return c.f;
}
__device__ __forceinline__ unsigned short f2bf(float f) {
    union { float f; unsigned int u; } c;
    c.f = f;
    unsigned int r = c.u + 0x7fffu + ((c.u >> 16) & 1u);  // RNE
    return (unsigned short)(r >> 16);
}
__device__ __forceinline__ float silu_fast(float x) {
    float e = __expf(-x);                       // v_exp_f32
    return x * __builtin_amdgcn_rcpf(1.0f + e); // v_rcp_f32
}
// Chunked-bijective XCD remap: hw block b runs on XCD (b%8); give each XCD a
// CONTIGUOUS range of logical tiles so panel-sharing neighbors co-reside in
// one L2. Requires nwg % 8 == 0 (all our grids satisfy this).
__device__ __forceinline__ int xcd_remap(int b, int nwg) {
    return (b & 7) * (nwg >> 3) + (b >> 3);
}

// ---------------------------------------------------------------------------
// PREP (merged): rmsnorm (blocks 0..8191), uvw pad-convert (8192..9343),
// o_w convert (9344..9855), rope tables (9856..9983). All independent.
// ---------------------------------------------------------------------------
__global__ __launch_bounds__(256) void prep_kernel(const float* __restrict__ x,
                                                   const float* __restrict__ ln_g,
                                                   unsigned short* __restrict__ xn,
                                                   const float* __restrict__ uv_w,
                                                   unsigned short* __restrict__ uvwb,
                                                   const float* __restrict__ o_w,
                                                   unsigned short* __restrict__ owb,
                                                   float* __restrict__ cost,
                                                   float* __restrict__ sint) {
    const int bid = blockIdx.x;
    const int tid = threadIdx.x;
    if (bid < 8192) {
        // rmsnorm: 4 rows per block
        int row  = bid * 4 + (tid >> 6);
        int lane = tid & 63;
        const float* xr = x + (size_t)row * H_DIM;
        floatx4 v0 = ((const floatx4*)xr)[lane];
        floatx4 v1 = ((const floatx4*)xr)[lane + 64];
        float ss = v0.x*v0.x + v0.y*v0.y + v0.z*v0.z + v0.w*v0.w
                 + v1.x*v1.x + v1.y*v1.y + v1.z*v1.z + v1.w*v1.w;
        #pragma unroll
        for (int off = 32; off > 0; off >>= 1) ss += __shfl_xor(ss, off, 64);
        float norm = sqrtf(ss) * 0.044194173824159216f;  // * H^-0.5
        float sc   = ln_g[0] / fmaxf(norm, 1e-5f);
        unsigned short* xo = xn + (size_t)row * H_DIM;
        ushortx4 o0, o1;
        o0.x = f2bf(v0.x * sc); o0.y = f2bf(v0.y * sc);
        o0.z = f2bf(v0.z * sc); o0.w = f2bf(v0.w * sc);
        o1.x = f2bf(v1.x * sc); o1.y = f2bf(v1.y * sc);
        o1.z = f2bf(v1.z * sc); o1.w = f2bf(v1.w * sc);
        ((ushortx4*)xo)[lane]      = o0;
        ((ushortx4*)xo)[lane + 64] = o1;
    } else if (bid < 9344) {
        // uvw f2bf with zero pad
        int i = (bid - 8192) * 256 + tid;
        ushortx4 o;
        if (i < UV_DIM * H_DIM / 4) {
            floatx4 v = ((const floatx4*)uv_w)[i];
            o.x = f2bf(v.x); o.y = f2bf(v.y); o.z = f2bf(v.z); o.w = f2bf(v.w);
        } else {
            o.x = 0; o.y = 0; o.z = 0; o.w = 0;
        }
        ((ushortx4*)uvwb)[i] = o;
    } else if (bid < 9856) {
        // o_w f2bf: exactly 512*256 = 131072 float4s
        int i = (bid - 9344) * 256 + tid;
        floatx4 v = ((const floatx4*)o_w)[i];
        ushortx4 o;
        o.x = f2bf(v.x); o.y = f2bf(v.y); o.z = f2bf(v.z); o.w = f2bf(v.w);
        ((ushortx4*)owb)[i] = o;
    } else {
        // rope tables: 128 blocks * 256 = 32768 = 512 s * 64 j
        int idx = (bid - 9856) * 256 + tid;
        int s = idx >> 6;
        int j = idx & 63;
        float invf = (float)pow(10000.0, (double)j / 64.0);
        float ang  = (float)s * invf;  // fp32 multiply like the f32 reference
        double a   = (double)ang;
        cost[s * 64 + j] = (float)cos(a);
        sint[s * 64 + j] = (float)sin(a);
    }
}

// ===========================================================================
// 128x256 pipelined GEMM core (r4-proven): 8 waves (2M x 4N),
// per-wave C = 64x64 (acc[4][4]). BK=32. 3 LDS bufs of 24 KiB = 72 KiB.
// Depth-2 prefetch, counted vmcnt(3) (0 only at final tile), 1 s_barrier per
// K-tile, setprio(1) around MFMA cluster, sched_barrier(0) pins.
// ===========================================================================
template <bool SWAPT>
__device__ __forceinline__ void gemm128_core(const unsigned short* __restrict__ A,
                                             const unsigned short* __restrict__ B,
                                             int lda, int ldb, int K,
                                             int m0, int n0,
                                             unsigned short (&st)[3][12288],
                                             floatx4 (&acc)[4][4]) {
    const int tid  = threadIdx.x;
    const int lane = tid & 63;
    const int wave = tid >> 6;
    const int quad = lane >> 4;
    const int l16  = lane & 15;
    const int wrow = (wave >> 2) * 64;
    const int wcol = (wave & 3) * 64;

    const int qa  = wave * 64 + lane;
    const int Ra  = qa >> 3;
    const int ca  = (qa & 7) ^ (Ra & 7);      // inverse swizzle
    const int srA = 2 * Ra + (ca >> 2);       // logical row 0..127
    const int scA = (ca & 3) * 8;             // k offset (shorts)
    const unsigned short* pa  = A + (size_t)(m0 + srA) * lda + scA;
    const unsigned short* pb0 = B + (size_t)(n0 + srA) * ldb + scA;
    const unsigned short* pb1 = pb0 + (size_t)128 * ldb;   // B rows 128..255
    const int ldsA  = (wave * 64) * 8;
    const int ldsB0 = 4096 + (wave * 64) * 8;
    const int ldsB1 = 4096 + (512 + wave * 64) * 8;

    #pragma unroll
    for (int i = 0; i < 4; i++)
        #pragma unroll
        for (int j = 0; j < 4; j++) acc[i][j] = (floatx4){0.f, 0.f, 0.f, 0.f};

    const int NT = K >> 5;
    auto stage = [&](int buf, int t) {
        unsigned short* s = &st[buf][0];
        const int kt = t * 32;
        ASYNC_CP16(pa  + kt, s + ldsA);
        ASYNC_CP16(pb0 + kt, s + ldsB0);
        ASYNC_CP16(pb1 + kt, s + ldsB1);
    };
    stage(0, 0);
    stage(1, 1);

    int aoff[4], boff[4];
    #pragma unroll
    for (int mt = 0; mt < 4; mt++) {
        int r  = wrow + mt * 16 + l16;        // 0..127
        int Rr = r >> 1;
        int cp = (((r & 1) << 2) + quad) ^ (Rr & 7);
        aoff[mt] = Rr * 64 + cp * 8;
    }
    #pragma unroll
    for (int nt = 0; nt < 4; nt++) {
        int r  = wcol + nt * 16 + l16;        // 0..255
        int Rr = r >> 1;
        int cp = (((r & 1) << 2) + quad) ^ (Rr & 7);
        boff[nt] = 4096 + Rr * 64 + cp * 8;
    }

    int bc = 0, bs = 2;
    for (int t = 0; t < NT; ++t) {
        if (t < NT - 1) asm volatile("s_waitcnt vmcnt(3)" ::: "memory");
        else            asm volatile("s_waitcnt vmcnt(0)" ::: "memory");
        __builtin_amdgcn_sched_barrier(0);   // pin: nothing crosses the wait
        __builtin_amdgcn_s_barrier();
        __builtin_amdgcn_sched_barrier(0);   // pin: ds_reads stay below barrier
        if (t + 2 < NT) stage(bs, t + 2);

        const unsigned short* sb = &st[bc][0];
        short8 af[4], bf[4];
        #pragma unroll
        for (int mt = 0; mt < 4; mt++) {
            union { short8 s8; uintx4 u4; } fu;
            fu.u4 = *(const uintx4*)&sb[aoff[mt]];
            af[mt] = fu.s8;
        }
        #pragma unroll
        for (int nt = 0; nt < 4; nt++) {
            union { short8 s8; uintx4 u4; } fu;
            fu.u4 = *(const uintx4*)&sb[boff[nt]];
            bf[nt] = fu.s8;
        }
        __builtin_amdgcn_s_setprio(1);
        #pragma unroll
        for (int mt = 0; mt < 4; mt++)
            #pragma unroll
            for (int nt = 0; nt < 4; nt++)
                acc[mt][nt] = SWAPT
                    ? __builtin_amdgcn_mfma_f32_16x16x32_bf16(bf[nt], af[mt], acc[mt][nt], 0, 0, 0)
                    : __builtin_amdgcn_mfma_f32_16x16x32_bf16(af[mt], bf[nt], acc[mt][nt], 0, 0, 0);
        __builtin_amdgcn_s_setprio(0);

        bc = (bc == 2) ? 0 : bc + 1;
        bs = (bs == 2) ? 0 : bs + 1;
    }
}

// LDS: staging (72 KiB) unioned with the epilogue transpose tile (64 KiB)
// and the fp32 RoPE tile Tf[128][132] (66 KiB, stride-132 anti-conflict).
union __align__(16) Lds3 {
    unsigned short st[3][12288];   // 73728 B staging
    unsigned short T[128 * 256];   // 65536 B epilogue
    float          Tf[128][132];   // 67584 B rope tile
};

// ---------------------------------------------------------------------------
// GEMM1 (merged): act = silu(xn @ uv_w^T + uv_b), grid (9, 256) xcd-remapped
//   xb <  4 : u columns, SWAPPED, swizzled LDS transpose, b128 stores
//   xb 4..7 : v columns, UNSWAPPED, T[n][m] transpose -> vT (b,e,s)
//   xb == 8 : base columns, UNSWAPPED, + FUSED ROPE -> q,k direct
// ---------------------------------------------------------------------------
__global__ __launch_bounds__(512, 2) void gemm1_128_kernel(const unsigned short* __restrict__ xn,
                                                           const unsigned short* __restrict__ uvw,
                                                           const float* __restrict__ uvb,
                                                           unsigned short* __restrict__ u,
                                                           unsigned short* __restrict__ vT,
                                                           const float* __restrict__ gamma,
                                                           const float* __restrict__ beta,
                                                           const float* __restrict__ cost,
                                                           const float* __restrict__ sint,
                                                           unsigned short* __restrict__ q,
                                                           unsigned short* __restrict__ k) {
    __shared__ Lds3 lds;
    floatx4 acc[4][4];
    const int bl = blockIdx.y * 9 + blockIdx.x;
    const int lg = xcd_remap(bl, 9 * (M_TOT / 128));  // 2304
    const int xb = lg % 9;
    const int m0 = (lg / 9) * 128;
    const int tid = threadIdx.x, lane = tid & 63, wave = tid >> 6;
    const int quad = lane >> 4, l16 = lane & 15;
    const int wrow = (wave >> 2) * 64, wcol = (wave & 3) * 64;

    if (xb < 4) {
        const int n0 = xb * 256;
        gemm128_core<true>(xn, uvw, H_DIM, H_DIM, H_DIM, m0, n0, lds.st, acc);
        __syncthreads();
        #pragma unroll
        for (int mt = 0; mt < 4; mt++) {
            int row = wrow + mt * 16 + l16;           // 0..127
            #pragma unroll
            for (int nt = 0; nt < 4; nt++) {
                int nl = wcol + nt * 16 + quad * 4;   // 0..255
                floatx4 b4 = *(const floatx4*)&uvb[n0 + nl];
                ushortx4 pk;
                #pragma unroll
                for (int r = 0; r < 4; r++)
                    pk[r] = f2bf(silu_fast(acc[mt][nt][r] + b4[r]));
                *(uintx2*)&lds.T[row * 256 + (((nl >> 3) ^ (row & 15)) << 3) + (nl & 7)] = *(uintx2*)&pk;
            }
        }
        __syncthreads();
        #pragma unroll
        for (int i = 0; i < 8; i++) {
            int idx = tid + i * 512;                  // 0..4095
            int row = idx >> 5, c16 = idx & 31;
            *(uintx4*)(u + (size_t)(m0 + row) * E_DIMC + n0 + c16 * 8) =
                *(const uintx4*)&lds.T[row * 256 + ((c16 ^ (row & 15)) << 3)];
        }
    } else if (xb < 8) {
        const int n0 = xb * 256;  // 1024..1792 in act space
        gemm128_core<false>(xn, uvw, H_DIM, H_DIM, H_DIM, m0, n0, lds.st, acc);
        __syncthreads();
        #pragma unroll
        for (int nt = 0; nt < 4; nt++) {
            int rowT = wcol + nt * 16 + l16;          // n-local 0..255
            float bias = uvb[n0 + rowT];
            #pragma unroll
            for (int mt = 0; mt < 4; mt++) {
                int colT = wrow + mt * 16 + quad * 4; // m-local 0..127
                ushortx4 pk;
                #pragma unroll
                for (int r = 0; r < 4; r++)
                    pk[r] = f2bf(silu_fast(acc[mt][nt][r] + bias));
                *(uintx2*)&lds.T[rowT * 128 + (((colT >> 3) ^ (rowT & 15)) << 3) + (colT & 7)] = *(uintx2*)&pk;
            }
        }
        __syncthreads();
        const int b = m0 >> 9, sg0 = m0 & (S_LEN - 1), eg0 = n0 - E_DIMC;
        #pragma unroll
        for (int i = 0; i < 8; i++) {
            int idx = tid + i * 512;                  // 0..4095
            int e = idx >> 4, j = idx & 15;
            *(uintx4*)(vT + ((size_t)b * E_DIMC + eg0 + e) * S_LEN + sg0 + j * 8) =
                *(const uintx4*)&lds.T[e * 128 + ((j ^ (e & 15)) << 3)];
        }
    } else {
        const int n0 = 2048;  // base slice; cols 128..255 hit zero-padded uvw
        gemm128_core<false>(xn, uvw, H_DIM, H_DIM, H_DIM, m0, n0, lds.st, acc);
        __syncthreads();   // staging LDS dead; safe to overwrite with Tf
        if ((wave & 3) < 2) {
            #pragma unroll
            for (int mt = 0; mt < 4; mt++) {
                int rowl = wrow + mt * 16 + quad * 4;     // 0..127 (rows rowl..+3)
                #pragma unroll
                for (int nt = 0; nt < 4; nt++) {
                    int n = wcol + nt * 16 + l16;         // 0..127
                    float bias = uvb[2048 + n];
                    #pragma unroll
                    for (int r = 0; r < 4; r++)
                        lds.Tf[rowl + r][n] = silu_fast(acc[mt][nt][r] + bias);
                }
            }
        }
        __syncthreads();
        // fused RoPE: 128 rows x 64 j pairs = 8192 items, 16 per thread
        #pragma unroll
        for (int i = 0; i < 16; i++) {
            int idx = tid + i * 512;         // 0..8191
            int row = idx >> 6, j = idx & 63;
            int s   = (m0 + row) & (S_LEN - 1);
            float b1 = lds.Tf[row][j];
            float b2 = lds.Tf[row][j + 64];
            float c  = cost[s * 64 + j];
            float sn = sint[s * 64 + j];
            float yq1 = b1 * gamma[j]       + beta[j];
            float yq2 = b2 * gamma[64 + j]  + beta[64 + j];
            float yk1 = b1 * gamma[128 + j] + beta[128 + j];
            float yk2 = b2 * gamma[192 + j] + beta[192 + j];
            size_t mo = (size_t)(m0 + row) * D_DIM;
            q[mo + j]      = f2bf(yq1 * c - yq2 * sn);
            q[mo + 64 + j] = f2bf(yq2 * c + yq1 * sn);
            k[mo + j]      = f2bf(yk1 * c - yk2 * sn);
            k[mo + 64 + j] = f2bf(yk2 * c + yk1 * sn);
        }
    }
}

// ===========================================================================
// 256x256 pipelined GEMM core (r3-proven): 8 waves (2M x 4N),
// per-wave C = 128x64 (acc[8][4]). BK=32. 4 LDS bufs (128 KiB), depth-3
// prefetch, counted vmcnt(8)/(4)/(0) tail, 1 s_barrier per K-tile,
// setprio(1) around MFMA clusters, sched_barrier(0) pins.
// ===========================================================================
template <bool SWAPT>
__device__ __forceinline__ void gemm256_core(const unsigned short* __restrict__ A,
                                             const unsigned short* __restrict__ B,
                                             int lda, int ldb, int K,
                                             int m0, int n0,
                                             unsigned short (&st)[4][2][128][64],
                                             floatx4 (&acc)[8][4]) {
    const int tid  = threadIdx.x;
    const int lane = tid & 63;
    const int wave = tid >> 6;
    const int quad = lane >> 4;
    const int l16  = lane & 15;
    const int wrow = (wave >> 2) * 128;
    const int wcol = (wave & 3) * 64;

    const int q0    = wave * 128 + lane;        // linear 16B chunk, i=0
    const int R0    = q0 >> 3;                  // LDS row (i=1: +8)
    const int cp0   = q0 & 7;                   // physical chunk in row
    const int c0    = cp0 ^ (R0 & 7);           // logical chunk (inverse swz)
    const int srow0 = 2 * R0 + (c0 >> 2);       // logical tile row (i=1: +16)
    const int scol0 = (c0 & 3) * 8;             // k-offset in shorts

    const unsigned short* pa0 = A + (size_t)(m0 + srow0) * lda + scol0;
    const unsigned short* pa1 = pa0 + (size_t)16 * lda;
    const unsigned short* pb0 = B + (size_t)(n0 + srow0) * ldb + scol0;
    const unsigned short* pb1 = pb0 + (size_t)16 * ldb;
    const int ldsOff0 = (wave * 128) * 8;       // ushort index of uniform base
    const int ldsOff1 = (wave * 128 + 64) * 8;

    #pragma unroll
    for (int i = 0; i < 8; i++)
        #pragma unroll
        for (int j = 0; j < 4; j++) acc[i][j] = (floatx4){0.f, 0.f, 0.f, 0.f};

    const int NT = K >> 5;
    auto stage = [&](int t) {
        unsigned short* sA = &st[t & 3][0][0][0];
        unsigned short* sB = &st[t & 3][1][0][0];
        const int kt = t * 32;
        ASYNC_CP16(pa0 + kt, sA + ldsOff0);
        ASYNC_CP16(pa1 + kt, sA + ldsOff1);
        ASYNC_CP16(pb0 + kt, sB + ldsOff0);
        ASYNC_CP16(pb1 + kt, sB + ldsOff1);
    };
    stage(0);
    stage(1);
    stage(2);

    int aoff[8], boff[4];
    #pragma unroll
    for (int mt = 0; mt < 8; mt++) {
        int r  = wrow + mt * 16 + l16;
        int Rr = r >> 1;
        int cp = (((r & 1) << 2) + quad) ^ (Rr & 7);
        aoff[mt] = Rr * 64 + cp * 8;
    }
    #pragma unroll
    for (int nt = 0; nt < 4; nt++) {
        int r  = wcol + nt * 16 + l16;
        int Rr = r >> 1;
        int cp = (((r & 1) << 2) + quad) ^ (Rr & 7);
        boff[nt] = Rr * 64 + cp * 8;
    }

    for (int t = 0; t < NT; ++t) {
        if (t < NT - 2)       asm volatile("s_waitcnt vmcnt(8)" ::: "memory");
        else if (t == NT - 2) asm volatile("s_waitcnt vmcnt(4)" ::: "memory");
        else                  asm volatile("s_waitcnt vmcnt(0)" ::: "memory");
        __builtin_amdgcn_sched_barrier(0);
        __builtin_amdgcn_s_barrier();
        __builtin_amdgcn_sched_barrier(0);
        if (t + 3 < NT) stage(t + 3);

        const unsigned short* sA = &st[t & 3][0][0][0];
        const unsigned short* sB = &st[t & 3][1][0][0];
        short8 bf[4];
        #pragma unroll
        for (int nt = 0; nt < 4; nt++) {
            union { short8 s8; uintx4 u4; } fu;
            fu.u4 = *(const uintx4*)&sB[boff[nt]];
            bf[nt] = fu.s8;
        }
        #pragma unroll
        for (int half = 0; half < 2; half++) {
            short8 af[4];
            #pragma unroll
            for (int mt = 0; mt < 4; mt++) {
                union { short8 s8; uintx4 u4; } fu;
                fu.u4 = *(const uintx4*)&sA[aoff[half * 4 + mt]];
                af[mt] = fu.s8;
            }
            __builtin_amdgcn_s_setprio(1);
            #pragma unroll
            for (int mt = 0; mt < 4; mt++)
                #pragma unroll
                for (int nt = 0; nt < 4; nt++)
                    acc[half * 4 + mt][nt] = SWAPT
                        ? __builtin_amdgcn_mfma_f32_16x16x32_bf16(bf[nt], af[mt], acc[half * 4 + mt][nt], 0, 0, 0)
                        : __builtin_amdgcn_mfma_f32_16x16x32_bf16(af[mt], bf[nt], acc[half * 4 + mt][nt], 0, 0, 0);
            __builtin_amdgcn_s_setprio(0);
        }
    }
}

// staging (128 KiB) unioned with 256x256 bf16 epilogue tile (128 KiB).
union __align__(16) Lds256 {
    unsigned short st[4][2][128][64];   // 131072 B staging
    unsigned short T[256 * 256];        // 131072 B epilogue
};

// ---------------------------------------------------------------------------
// OUT: out = oe @ o_w^T + o_b + x, 256^2 pipelined core, direct f32 stores.
// 256 blocks (xcd-remapped: each XCD owns 16 m-panels; ow 1 MB L2-resident).
// ---------------------------------------------------------------------------
__global__ __launch_bounds__(512, 2) void gemm_out256_kernel(const unsigned short* __restrict__ oe,
                                                             const unsigned short* __restrict__ ow,
                                                             const float* __restrict__ ob,
                                                             const float* __restrict__ x,
                                                             float* __restrict__ out) {
    __shared__ __align__(16) unsigned short st[4][2][128][64];
    floatx4 acc[8][4];
    const int bl = blockIdx.y * 2 + blockIdx.x;
    const int lg = xcd_remap(bl, 2 * (M_TOT / 256)); // 256
    const int n0 = (lg & 1) * 256;
    const int m0 = (lg >> 1) * 256;
    gemm256_core<true>(oe, ow, E_DIMC, E_DIMC, E_DIMC, m0, n0, st, acc);

    const int tid = threadIdx.x, lane = tid & 63, wave = tid >> 6;
    const int quad = lane >> 4, l16 = lane & 15;
    const int wrow = (wave >> 2) * 128, wcol = (wave & 3) * 64;
    #pragma unroll
    for (int mt = 0; mt < 8; mt++) {
        int m = m0 + wrow + mt * 16 + l16;
        #pragma unroll
        for (int nt = 0; nt < 4; nt++) {
            int n = n0 + wcol + nt * 16 + quad * 4;
            size_t off = (size_t)m * H_DIM + n;
            floatx4 b4 = *(const floatx4*)&ob[n];
            floatx4 x4 = *(const floatx4*)&x[off];
            *(floatx4*)&out[off] = acc[mt][nt] + b4 + x4;
        }
    }
}

// ---------------------------------------------------------------------------
// PV: u <- u .* (P @ v), 256^2 pipelined core, r2-verified swizzled 256^2
// transpose epilogue, coalesced b128 RMW. grid (2m, 4n, 64b) = 512 blocks
// xcd-remapped: each XCD owns 8 whole batches.
// ---------------------------------------------------------------------------
__global__ __launch_bounds__(512, 2) void gemm_pv256_kernel(const unsigned short* __restrict__ P,
                                                            const unsigned short* __restrict__ vT,
                                                            unsigned short* __restrict__ u) {
    __shared__ Lds256 lds;
    floatx4 acc[8][4];
    const int bl = (blockIdx.z * 4 + blockIdx.y) * 2 + blockIdx.x;
    const int lg = xcd_remap(bl, 512);
    const int bx = lg & 1, by = (lg >> 1) & 3, bb = lg >> 3;
    const unsigned short* Pb  = P  + (size_t)bb * S_LEN * S_LEN;
    const unsigned short* vTb = vT + (size_t)bb * E_DIMC * S_LEN;
    const int m0 = bx * 256, n0 = by * 256;
    gemm256_core<true>(Pb, vTb, S_LEN, S_LEN, S_LEN, m0, n0, lds.st, acc);

    const int tid = threadIdx.x, lane = tid & 63, wave = tid >> 6;
    const int quad = lane >> 4, l16 = lane & 15;
    const int wrow = (wave >> 2) * 128, wcol = (wave & 3) * 64;
    __syncthreads();   // staging LDS dead; reuse as T
    #pragma unroll
    for (int mt = 0; mt < 8; mt++) {
        int row = wrow + mt * 16 + l16;               // 0..255
        #pragma unroll
        for (int nt = 0; nt < 4; nt++) {
            int nl = wcol + nt * 16 + quad * 4;       // 0..255
            ushortx4 pk;
            #pragma unroll
            for (int r = 0; r < 4; r++) pk[r] = f2bf(acc[mt][nt][r]);
            *(uintx2*)&lds.T[row * 256 + (((nl >> 3) ^ (row & 15)) & 31) * 8 + (nl & 7)] = *(uintx2*)&pk;
        }
    }
    __syncthreads();
    #pragma unroll
    for (int i = 0; i < 16; i++) {
        int idx = tid + i * 512;                      // 0..8191
        int row = idx >> 5, c16 = idx & 31;
        size_t off = ((size_t)bb * S_LEN + m0 + row) * E_DIMC + n0 + c16 * 8;
        union { uintx4 u4; unsigned short s[8]; } tv, uv, ov;
        tv.u4 = *(const uintx4*)&lds.T[row * 256 + ((c16 ^ (row & 15)) * 8)];
        uv.u4 = *(const uintx4*)(u + off);
        #pragma unroll
        for (int jj = 0; jj < 8; jj++) ov.s[jj] = f2bf(bf2f(tv.s[jj]) * bf2f(uv.s[jj]));
        *(uintx4*)(u + off) = ov.u4;
    }
}

// ---------------------------------------------------------------------------
// qk: P = relu((q k^T + w_bias)/sqrt(128))^2, 128x256 pipelined core (K=128 =
// 4 BK=32 tiles, depth-2), swizzled transpose epilogue, b128 stores.
// grid (4m, 2n, 64b) = 512 blocks xcd-remapped: 8 whole batches per XCD.
// ---------------------------------------------------------------------------
__global__ __launch_bounds__(512, 2) void gemm_qk128_kernel(const unsigned short* __restrict__ q,
                                                            const unsigned short* __restrict__ k,
                                                            const float* __restrict__ wbias,
                                                            unsigned short* __restrict__ P) {
    __shared__ Lds3 lds;
    floatx4 acc[4][4];
    const int bl = (blockIdx.z * 2 + blockIdx.y) * 4 + blockIdx.x;
    const int lg = xcd_remap(bl, 512);
    const int bx = lg & 3, by = (lg >> 2) & 1, bz = lg >> 3;
    size_t boff = (size_t)bz * S_LEN * D_DIM;
    unsigned short* Pb = P + (size_t)bz * S_LEN * S_LEN;
    const int m0 = bx * 128, n0 = by * 256;
    gemm128_core<true>(q + boff, k + boff, D_DIM, D_DIM, D_DIM, m0, n0, lds.st, acc);

    const int tid = threadIdx.x, lane = tid & 63, wave = tid >> 6;
    const int quad = lane >> 4, l16 = lane & 15;
    const int wrow = (wave >> 2) * 64, wcol = (wave & 3) * 64;
    __syncthreads();
    #pragma unroll
    for (int mt = 0; mt < 4; mt++) {
        int row = wrow + mt * 16 + l16;               // 0..127
        int s   = m0 + row;
        #pragma unroll
        for (int nt = 0; nt < 4; nt++) {
            int nl = wcol + nt * 16 + quad * 4;       // 0..255
            int t0 = n0 + nl;
            ushortx4 pk;
            #pragma unroll
            for (int r = 0; r < 4; r++) {
                float z = (acc[mt][nt][r] + wbias[t0 + r - s + (S_LEN - 1)]) * 0.08838834764831845f;
                z = fmaxf(z, 0.f);
                pk[r] = f2bf(z * z);
            }
            *(uintx2*)&lds.T[row * 256 + (((nl >> 3) ^ (row & 15)) << 3) + (nl & 7)] = *(uintx2*)&pk;
        }
    }
    __syncthreads();
    #pragma unroll
    for (int i = 0; i < 8; i++) {
        int idx = tid + i * 512;                      // 0..4095
        int row = idx >> 5, c16 = idx & 31;
        *(uintx4*)(Pb + (size_t)(m0 + row) * S_LEN + n0 + c16 * 8) =
            *(const uintx4*)&lds.T[row * 256 + ((c16 ^ (row & 15)) << 3)];
    }
}

// ---------------------------------------------------------------------------
extern "C" void kernel_launch(void* const* d_in, const int* in_sizes, int n_in,
                              void* d_out, int out_size, void* d_ws, size_t ws_size,
                              hipStream_t stream) {
    const float* x     = (const float*)d_in[0];
    const float* ln_g  = (const float*)d_in[1];
    const float* uv_w  = (const float*)d_in[2];
    const float* uv_b  = (const float*)d_in[3];
    const float* gamma = (const float*)d_in[4];
    const float* beta  = (const float*)d_in[5];
    const float* wbias = (const float*)d_in[6];
    const float* o_w   = (const float*)d_in[7];
    const float* o_b   = (const float*)d_in[8];
    float* out = (float*)d_out;

    char* ws = (char*)d_ws;
    size_t off = 0;
    auto alloc = [&](size_t bytes) {
        void* p = ws + off;
        off += (bytes + 255) & ~(size_t)255;
        return p;
    };
    // Peak ~180 MiB:
    unsigned short* u     = (unsigned short*)alloc((size_t)M_TOT * E_DIMC * 2);      // 64 MiB (u, then oe in place)
    unsigned short* vT    = (unsigned short*)alloc((size_t)64 * E_DIMC * S_LEN * 2); // 64 MiB
    unsigned short* xn    = (unsigned short*)alloc((size_t)M_TOT * H_DIM * 2);       // 32 MiB
    unsigned short* P     = xn;                                                      // alias (xn dead after gemm1)
    unsigned short* q     = (unsigned short*)alloc((size_t)M_TOT * D_DIM * 2);       // 8 MiB
    unsigned short* k     = (unsigned short*)alloc((size_t)M_TOT * D_DIM * 2);       // 8 MiB
    float*          cost  = (float*)alloc((size_t)S_LEN * 64 * 4);
    float*          sint  = (float*)alloc((size_t)S_LEN * 64 * 4);
    unsigned short* uvwb  = (unsigned short*)alloc((size_t)UV_PAD * H_DIM * 2);      // 2.25 MiB (zero-padded)
    unsigned short* owb   = (unsigned short*)alloc((size_t)H_DIM * E_DIMC * 2);      // 1 MiB
    (void)ws_size; (void)in_sizes; (void)n_in; (void)out_size;

    // prep (merged): rmsnorm + uvw pad-convert + o_w convert + rope tables
    prep_kernel<<<9984, 256, 0, stream>>>(x, ln_g, xn, uv_w, uvwb, o_w, owb, cost, sint);

    // gemm1 + silu + fused rope (128x256 pipelined): u / vT / q,k
    gemm1_128_kernel<<<dim3(9, M_TOT / 128), 512, 0, stream>>>(
        xn, uvwb, uv_b, u, vT, gamma, beta, cost, sint, q, k);

    // P = relu^2((q k^T + bias)/sqrt(128))   (overwrites xn region)
    gemm_qk128_kernel<<<dim3(4, 2, 64), 512, 0, stream>>>(q, k, wbias, P);

    // u <- u .* (P @ v)  in place (256^2 pipelined)
    gemm_pv256_kernel<<<dim3(2, 4, 64), 512, 0, stream>>>(P, vT, u);

    // out = oe @ o_w^T + o_b + x (256^2 pipelined, r3-best)
    gemm_out256_kernel<<<dim3(H_DIM / 256, M_TOT / 256), 512, 0, stream>>>(u, owb, o_b, x, out);
}